// Round 11
// baseline (393.971 us; speedup 1.0000x reference)
//
#include <hip/hip_runtime.h>
#include <hip/hip_bf16.h>

#define NN 50000
#define NE 800000
#define F 128     // input feature dim (= K)
#define HD 128    // output dim = H*DH (= N)
#define H 4

typedef __attribute__((ext_vector_type(4))) float f32x4;
typedef __attribute__((ext_vector_type(8))) __bf16 bf16x8;
typedef __attribute__((ext_vector_type(2))) __bf16 bf16x2;

// ---------- helpers ----------

// mish(x) = x * tanh(softplus(x)) = x * (u-1)/(u+1), u = (1+e^x)^2
__device__ __forceinline__ float mish_f(float x) {
    if (x > 30.f) return x;
    float t = __expf(x);
    float u = 1.f + t;
    u = u * u;
    return x * (u - 1.f) * __builtin_amdgcn_rcpf(u + 1.f);
}

// packed f32x2 -> bf16x2 (compiler emits v_cvt_pk_bf16_f32, RNE)
__device__ __forceinline__ unsigned pack2_bf16(float a, float b) {
    bf16x2 v;
    v.x = (__bf16)a;
    v.y = (__bf16)b;
    return __builtin_bit_cast(unsigned, v);
}
__device__ __forceinline__ float bf16lo_to_f32(unsigned p) {
    return __uint_as_float((p & 0xFFFFu) << 16);
}
__device__ __forceinline__ float bf16hi_to_f32(unsigned p) {
    return __uint_as_float(p & 0xFFFF0000u);
}

// ---------- prep: W -> bf16 fragment-ordered; extra blocks zero cnt/cnt2 ----------
__global__ __launch_bounds__(256) void prep_w(
    const float* __restrict__ W0, const float* __restrict__ W1,
    const float* __restrict__ W2, uint4* __restrict__ O,
    uint4* __restrict__ zero_dst)   // 400,000 B = 25,000 uint4
{
    int b = blockIdx.x;
    if (b >= 3) {
        int i = (b - 3) * 256 + threadIdx.x;
        if (i < 25000) zero_dst[i] = make_uint4(0, 0, 0, 0);
        return;
    }
    const float* W = (b == 0) ? W0 : (b == 1) ? W1 : W2;
    uint4* out = O + b * 2048;
    for (int c = threadIdx.x; c < 2048; c += 256) {
        int fn = c >> 8, ks = (c >> 6) & 3, lane = c & 63;
        int lgp = lane >> 4, l15 = lane & 15;
        int col = fn * 16 + l15, k0 = ks * 32 + lgp * 8;
        unsigned u[4];
        #pragma unroll
        for (int i = 0; i < 4; ++i)
            u[i] = pack2_bf16(W[(k0 + 2 * i) * 128 + col],
                              W[(k0 + 2 * i + 1) * 128 + col]);
        out[c] = make_uint4(u[0], u[1], u[2], u[3]);
    }
}

// ---------- CSR build ----------
__global__ __launch_bounds__(256) void hist_kernel(
    const int* __restrict__ receivers, unsigned* __restrict__ cnt)
{
    int i = blockIdx.x * 256 + threadIdx.x;
    if (i < NE) atomicAdd(&cnt[receivers[i]], 1u);
}

// scan phase 1: per-block exclusive scan of 256 counts + block sum
__global__ __launch_bounds__(256) void scan1_kernel(
    const unsigned* __restrict__ cnt, unsigned* __restrict__ rowptr,
    unsigned* __restrict__ bsum)
{
    __shared__ unsigned sh[256];
    const int t = threadIdx.x;
    int i = blockIdx.x * 256 + t;
    unsigned c = (i < NN) ? cnt[i] : 0u;
    sh[t] = c;
    __syncthreads();
    unsigned incl = c;
    for (int off = 1; off < 256; off <<= 1) {
        unsigned v = (t >= off) ? sh[t - off] : 0u;
        __syncthreads();
        incl += v;
        sh[t] = incl;
        __syncthreads();
    }
    if (i < NN) rowptr[i] = incl - c;      // exclusive within block
    if (t == 255) bsum[blockIdx.x] = incl; // block total
}

// scan phase 2+3 fused: each block redundantly scans the block sums,
// picks its own offset, adds it.
__global__ __launch_bounds__(256) void scan3_kernel(
    unsigned* __restrict__ rowptr, const unsigned* __restrict__ bsum, int nb)
{
    __shared__ unsigned sh[256];
    __shared__ unsigned s_off;
    const int t = threadIdx.x;
    unsigned c = (t < nb) ? bsum[t] : 0u;
    sh[t] = c;
    __syncthreads();
    unsigned incl = c;
    for (int off = 1; off < 256; off <<= 1) {
        unsigned v = (t >= off) ? sh[t - off] : 0u;
        __syncthreads();
        incl += v;
        sh[t] = incl;
        __syncthreads();
    }
    if (t == 0) {
        s_off = (blockIdx.x > 0) ? sh[blockIdx.x - 1] : 0u;
        if (blockIdx.x == 0) rowptr[NN] = NE;
    }
    __syncthreads();
    int i = blockIdx.x * 256 + t;
    if (i < NN) rowptr[i] += s_off;
}

// scatter + inverse map jof: edge e lands at perm position jof[e]
__global__ __launch_bounds__(256) void scatter_kernel(
    const int* __restrict__ receivers, const unsigned* __restrict__ rowptr,
    unsigned* __restrict__ cnt2, unsigned* __restrict__ jof)
{
    int i = blockIdx.x * 256 + threadIdx.x;
    if (i >= NE) return;
    int r = receivers[i];
    unsigned pos = rowptr[r] + atomicAdd(&cnt2[r], 1u);
    jof[i] = pos;
}

// ---------- both node projections in one kernel ----------
// Sp/Rp layout (bf16, head-interleaved): node row = 64 uints (256 B);
// uint k = l15*4 + h holds cols (32h + l15, 32h + 16 + l15) as 2 bf16.
__global__ __launch_bounds__(256, 4) void proj_both(
    const float* __restrict__ X,
    const bf16x8* __restrict__ Wf0, const bf16x8* __restrict__ Wf1,
    const float* __restrict__ b0, const float* __restrict__ b1,
    int M, uint2* __restrict__ Sp, uint2* __restrict__ Rp)
{
    __shared__ __align__(16) char ldsA[32768];
    const int t = threadIdx.x;
    const int lane = t & 63;
    const int wid = t >> 6;
    const int wr = wid >> 1, wc = wid & 1;
    const int l15 = lane & 15, lgp = lane >> 4;
    const size_t rowbase = (size_t)blockIdx.x * 128;

    #pragma unroll
    for (int i = 0; i < 8; ++i) {
        int c = i * 256 + t;
        int row = c >> 4, cc = c & 15;
        size_t e = rowbase + row;
        uint4 p = make_uint4(0, 0, 0, 0);
        if (e < (size_t)M) {
            const float4* src = (const float4*)(X + e * F + cc * 8);
            float4 f0 = src[0], f1 = src[1];
            p.x = pack2_bf16(f0.x, f0.y);
            p.y = pack2_bf16(f0.z, f0.w);
            p.z = pack2_bf16(f1.x, f1.y);
            p.w = pack2_bf16(f1.z, f1.w);
        }
        unsigned byte = (unsigned)(row * 256 + cc * 16);
        byte ^= (unsigned)((row & 7) << 4);
        *(uint4*)(ldsA + byte) = p;
    }
    __syncthreads();

    #pragma unroll
    for (int pass = 0; pass < 2; ++pass) {
        const bf16x8* Wf = pass ? Wf1 : Wf0;
        const float* bias = pass ? b1 : b0;
        uint2* Y = pass ? Rp : Sp;

        f32x4 acc[4][4];
        #pragma unroll
        for (int n = 0; n < 4; ++n) {
            float bv = bias[wc * 64 + n * 16 + l15];
            #pragma unroll
            for (int m = 0; m < 4; ++m) {
                acc[m][n][0] = bv; acc[m][n][1] = bv;
                acc[m][n][2] = bv; acc[m][n][3] = bv;
            }
        }
        #pragma unroll
        for (int ks = 0; ks < 4; ++ks) {
            const int kb = ks * 64 + lgp * 16;
            bf16x8 af[4], bfr[4];
            #pragma unroll
            for (int m = 0; m < 4; ++m) {
                int row = wr * 64 + m * 16 + l15;
                unsigned byte = ((unsigned)(row * 256 + kb)) ^ ((row & 7) << 4);
                af[m] = *(const bf16x8*)(ldsA + byte);
            }
            #pragma unroll
            for (int n = 0; n < 4; ++n)
                bfr[n] = Wf[((wc * 4 + n) * 4 + ks) * 64 + lane];
            #pragma unroll
            for (int m = 0; m < 4; ++m)
                #pragma unroll
                for (int n = 0; n < 4; ++n)
                    acc[m][n] = __builtin_amdgcn_mfma_f32_16x16x32_bf16(
                        af[m], bfr[n], acc[m][n], 0, 0, 0);
        }
        // store: this thread's cols are heads wc*2 + {0,1}, col-class l15
        #pragma unroll
        for (int m = 0; m < 4; ++m)
            #pragma unroll
            for (int j = 0; j < 4; ++j) {
                int row = wr * 64 + m * 16 + lgp * 4 + j;
                size_t e = rowbase + row;
                if (e >= (size_t)M) continue;
                uint2 pk;
                pk.x = pack2_bf16(acc[m][0][j], acc[m][1][j]);
                pk.y = pack2_bf16(acc[m][2][j], acc[m][3][j]);
                Y[e * 32 + l15 * 2 + wc] = pk;   // uints k = l15*4 + wc*2 + {0,1}
            }
    }
}

// ---------- edge GEMM: BM=64, minimal tail, 8 blocks/CU ----------
// 4 waves/block, wave w owns rows w*16..w*16+15 across all 128 cols.
// EA row layout (bf16): uint k = l15*4 + h holds cols (32h+l15, 32h+16+l15).
__global__ __launch_bounds__(256, 8) void edge_gemm(
    const float* __restrict__ X, const bf16x8* __restrict__ Wf,
    const float* __restrict__ bias,
    const int* __restrict__ senders, const unsigned* __restrict__ jof,
    const uint4* __restrict__ Sp4, uint4* __restrict__ EAp)
{
    __shared__ __align__(16) char ldsA[16384];
    const int t = threadIdx.x;
    const int lane = t & 63;
    const int wid = t >> 6;
    const int l15 = lane & 15, lgp = lane >> 4;
    const size_t rowbase = (size_t)blockIdx.x * 64;

    // ---- stage A: 64 edge rows -> bf16, XOR-swizzled (16 KB) ----
    #pragma unroll
    for (int i = 0; i < 4; ++i) {
        int c = i * 256 + t;
        int row = c >> 4, cc = c & 15;
        const float4* src = (const float4*)(X + (rowbase + row) * F + cc * 8);
        float4 f0 = src[0], f1 = src[1];
        uint4 p;
        p.x = pack2_bf16(f0.x, f0.y);
        p.y = pack2_bf16(f0.z, f0.w);
        p.z = pack2_bf16(f1.x, f1.y);
        p.w = pack2_bf16(f1.z, f1.w);
        unsigned byte = (unsigned)(row * 256 + cc * 16);
        byte ^= (unsigned)((row & 7) << 4);
        *(uint4*)(ldsA + byte) = p;
    }

    f32x4 acc[8];
    #pragma unroll
    for (int n = 0; n < 8; ++n) {
        float bv = bias[n * 16 + l15];
        acc[n][0] = bv; acc[n][1] = bv; acc[n][2] = bv; acc[n][3] = bv;
    }
    __syncthreads();

    // ---- MFMA: A from LDS, B straight from L2-resident fragment buffer ----
    #pragma unroll
    for (int ks = 0; ks < 4; ++ks) {
        int arow = wid * 16 + l15;
        unsigned abyte = ((unsigned)(arow * 256 + ks * 64 + lgp * 16))
                         ^ ((arow & 7) << 4);
        bf16x8 af = *(const bf16x8*)(ldsA + abyte);
        #pragma unroll
        for (int n = 0; n < 8; ++n) {
            bf16x8 bfr = Wf[(n * 4 + ks) * 64 + lane];
            acc[n] = __builtin_amdgcn_mfma_f32_16x16x32_bf16(af, bfr, acc[n], 0, 0, 0);
        }
    }

    // ---- tail: 4 rows per thread (row = wid*16 + lgp*4 + j) ----
    #pragma unroll
    for (int j = 0; j < 4; ++j) {
        int row = wid * 16 + lgp * 4 + j;
        size_t e = rowbase + row;
        int snd = senders[e];          // 16-lane broadcast loads
        unsigned jj = jof[e];
        uint4 sv = Sp4[(size_t)snd * 16 + l15];
        unsigned uo[4];
        #pragma unroll
        for (int h = 0; h < 4; ++h) {
            unsigned sp = (h == 0) ? sv.x : (h == 1) ? sv.y : (h == 2) ? sv.z : sv.w;
            float elo = acc[2 * h][j]     + bf16lo_to_f32(sp);
            float ehi = acc[2 * h + 1][j] + bf16hi_to_f32(sp);
            uo[h] = pack2_bf16(elo, ehi);
        }
        EAp[(size_t)jj * 16 + l15] = make_uint4(uo[0], uo[1], uo[2], uo[3]);
    }
}

// ---------- fused logit + single-pass softmax + aggregate ----------
// 16 receivers per block, 4 per wave: each 16-lane group owns one receiver.
// Lane q reads uint4 EA[j*16+q] (heads 0..3, col-class q) -> coalesced
// 256B row read per group per edge.
__global__ __launch_bounds__(256) void agg_kernel(
    const unsigned* __restrict__ rowptr,
    const uint4* __restrict__ Rp4,
    const float* __restrict__ attw, const float* __restrict__ attb,
    const uint4* __restrict__ EA4, float* __restrict__ out)
{
    const int lane = threadIdx.x & 63;
    const int wid  = threadIdx.x >> 6;
    const int g    = lane >> 4;     // receiver slot within wave
    const int q    = lane & 15;     // col class
    const int r = blockIdx.x * 16 + wid * 4 + g;
    if (r >= NN) return;
    const unsigned start = rowptr[r], end = rowptr[r + 1];
    float* orow = out + (size_t)r * HD;

    if (start == end) {
        #pragma unroll
        for (int h = 0; h < 4; ++h) {
            orow[32 * h + q] = 0.f;
            orow[32 * h + 16 + q] = 0.f;
        }
        return;
    }

    uint4 rv = Rp4[(size_t)r * 16 + q];
    float rlo[4], rhi[4];
    rlo[0] = bf16lo_to_f32(rv.x); rhi[0] = bf16hi_to_f32(rv.x);
    rlo[1] = bf16lo_to_f32(rv.y); rhi[1] = bf16hi_to_f32(rv.y);
    rlo[2] = bf16lo_to_f32(rv.z); rhi[2] = bf16hi_to_f32(rv.z);
    rlo[3] = bf16lo_to_f32(rv.w); rhi[3] = bf16hi_to_f32(rv.w);
    const float aw0 = attw[q];
    const float aw1 = attw[q + 16];
    const float ab0 = attb[0];

    float accl[4] = {0.f, 0.f, 0.f, 0.f};
    float acch[4] = {0.f, 0.f, 0.f, 0.f};
    float den[4]  = {0.f, 0.f, 0.f, 0.f};

    for (unsigned j = start; j < end; ++j) {
        uint4 p = EA4[(size_t)j * 16 + q];
        float el[4], eh[4], tt[4];
        el[0] = bf16lo_to_f32(p.x); eh[0] = bf16hi_to_f32(p.x);
        el[1] = bf16lo_to_f32(p.y); eh[1] = bf16hi_to_f32(p.y);
        el[2] = bf16lo_to_f32(p.z); eh[2] = bf16hi_to_f32(p.z);
        el[3] = bf16lo_to_f32(p.w); eh[3] = bf16hi_to_f32(p.w);
        #pragma unroll
        for (int h = 0; h < 4; ++h)
            tt[h] = mish_f(el[h] + rlo[h]) * aw0 + mish_f(eh[h] + rhi[h]) * aw1;
        #pragma unroll
        for (int o = 1; o < 16; o <<= 1) {
            tt[0] += __shfl_xor(tt[0], o);
            tt[1] += __shfl_xor(tt[1], o);
            tt[2] += __shfl_xor(tt[2], o);
            tt[3] += __shfl_xor(tt[3], o);
        }
        #pragma unroll
        for (int h = 0; h < 4; ++h) {
            float w = __expf(tt[h] + ab0);
            den[h]  += w;
            accl[h] += w * el[h];
            acch[h] += w * eh[h];
        }
    }
    #pragma unroll
    for (int h = 0; h < 4; ++h) {
        float rd = 1.f / den[h];
        orow[32 * h + q]      = accl[h] * rd;
        orow[32 * h + 16 + q] = acch[h] * rd;
    }
}

// ---------- host ----------
extern "C" void kernel_launch(void* const* d_in, const int* in_sizes, int n_in,
                              void* d_out, int out_size, void* d_ws, size_t ws_size,
                              hipStream_t stream) {
    const float* nodes = (const float*)d_in[0];
    const float* edges = (const float*)d_in[1];
    const float* Ws_k  = (const float*)d_in[2];
    const float* Ws_b  = (const float*)d_in[3];
    const float* Wr_k  = (const float*)d_in[4];
    const float* Wr_b  = (const float*)d_in[5];
    const float* We_k  = (const float*)d_in[6];
    const float* We_b  = (const float*)d_in[7];
    const float* attw  = (const float*)d_in[8];
    const float* attb  = (const float*)d_in[9];
    const int* senders   = (const int*)d_in[10];
    const int* receivers = (const int*)d_in[11];
    float* out = (float*)d_out;

    char* ws = (char*)d_ws;
    const size_t CNT_OFF  = 0;            // 200,000
    const size_t CNT2_OFF = 200000;       // 200,000
    const size_t RP_OFF   = 400000;       // 200,004
    const size_t BS_OFF   = 600004;       // 1,024 (bsum)
    const size_t JOF_OFF  = 700000;       // 3,200,000 -> ends 3,900,000
    const size_t WF_OFF   = 3900000;      // 98,304    -> ends 3,998,304
    const size_t SP_OFF   = 4000000;      // 12,800,000 (bf16) -> 16.8e6
    const size_t RPP_OFF  = 16800000;     // 12,800,000 -> 29.6e6
    const size_t EA_OFF   = 29600000;     // 204,800,000 -> 234.4e6

    unsigned* cnt    = (unsigned*)(ws + CNT_OFF);
    unsigned* cnt2   = (unsigned*)(ws + CNT2_OFF);
    unsigned* rowptr = (unsigned*)(ws + RP_OFF);
    unsigned* bsum   = (unsigned*)(ws + BS_OFF);
    unsigned* jof    = (unsigned*)(ws + JOF_OFF);
    uint4*    Wf     = (uint4*)(ws + WF_OFF);
    uint2*    Sp     = (uint2*)(ws + SP_OFF);
    uint2*    Rp     = (uint2*)(ws + RPP_OFF);
    unsigned* EA     = (unsigned*)(ws + EA_OFF);
    (void)ws_size;

    const int NB = (NN + 255) / 256;   // 196 scan blocks

    // weights -> bf16 fragment order; extra blocks zero cnt/cnt2
    prep_w<<<3 + 98, 256, 0, stream>>>(Ws_k, Wr_k, We_k, Wf, (uint4*)(ws + CNT_OFF));

    // CSR build (rowptr + inverse perm map jof), multi-block scan
    hist_kernel<<<(NE + 255) / 256, 256, 0, stream>>>(receivers, cnt);
    scan1_kernel<<<NB, 256, 0, stream>>>(cnt, rowptr, bsum);
    scan3_kernel<<<NB, 256, 0, stream>>>(rowptr, bsum, NB);
    scatter_kernel<<<(NE + 255) / 256, 256, 0, stream>>>(receivers, rowptr, cnt2, jof);

    // both node projections (bf16 head-interleaved packed output)
    proj_both<<<(NN + 127) / 128, 256, 0, stream>>>(
        nodes, (const bf16x8*)Wf, (const bf16x8*)(Wf + 2048),
        Ws_b, Wr_b, NN, Sp, Rp);

    // edge GEMM: EA written at perm positions (no logits, no R gather)
    edge_gemm<<<NE / 64, 256, 0, stream>>>(
        edges, (const bf16x8*)(Wf + 4096), We_b,
        senders, jof, (const uint4*)Sp, (uint4*)EA);

    // fused logit + single-pass softmax + aggregation (16 receivers/block)
    agg_kernel<<<(NN + 15) / 16, 256, 0, stream>>>(
        rowptr, (const uint4*)Rp, attw, attb, (const uint4*)EA, out);
}

// Round 12
// 393.560 us; speedup vs baseline: 1.0010x; 1.0010x over previous
//
#include <hip/hip_runtime.h>
#include <hip/hip_bf16.h>

#define NN 50000
#define NE 800000
#define F 128     // input feature dim (= K)
#define HD 128    // output dim = H*DH (= N)
#define H 4

typedef __attribute__((ext_vector_type(4))) float f32x4;
typedef __attribute__((ext_vector_type(8))) __bf16 bf16x8;
typedef __attribute__((ext_vector_type(2))) __bf16 bf16x2;

// ---------- helpers ----------

// mish(x) = x * tanh(softplus(x)) = x * (u-1)/(u+1), u = (1+e^x)^2
__device__ __forceinline__ float mish_f(float x) {
    if (x > 30.f) return x;
    float t = __expf(x);
    float u = 1.f + t;
    u = u * u;
    return x * (u - 1.f) * __builtin_amdgcn_rcpf(u + 1.f);
}

// packed f32x2 -> bf16x2 (compiler emits v_cvt_pk_bf16_f32, RNE)
__device__ __forceinline__ unsigned pack2_bf16(float a, float b) {
    bf16x2 v;
    v.x = (__bf16)a;
    v.y = (__bf16)b;
    return __builtin_bit_cast(unsigned, v);
}
__device__ __forceinline__ float bf16lo_to_f32(unsigned p) {
    return __uint_as_float((p & 0xFFFFu) << 16);
}
__device__ __forceinline__ float bf16hi_to_f32(unsigned p) {
    return __uint_as_float(p & 0xFFFF0000u);
}

// ---------- prep: W -> bf16 fragment-ordered; extra blocks zero cnt/cnt2 ----------
__global__ __launch_bounds__(256) void prep_w(
    const float* __restrict__ W0, const float* __restrict__ W1,
    const float* __restrict__ W2, uint4* __restrict__ O,
    uint4* __restrict__ zero_dst)   // 400,000 B = 25,000 uint4
{
    int b = blockIdx.x;
    if (b >= 3) {
        int i = (b - 3) * 256 + threadIdx.x;
        if (i < 25000) zero_dst[i] = make_uint4(0, 0, 0, 0);
        return;
    }
    const float* W = (b == 0) ? W0 : (b == 1) ? W1 : W2;
    uint4* out = O + b * 2048;
    for (int c = threadIdx.x; c < 2048; c += 256) {
        int fn = c >> 8, ks = (c >> 6) & 3, lane = c & 63;
        int lgp = lane >> 4, l15 = lane & 15;
        int col = fn * 16 + l15, k0 = ks * 32 + lgp * 8;
        unsigned u[4];
        #pragma unroll
        for (int i = 0; i < 4; ++i)
            u[i] = pack2_bf16(W[(k0 + 2 * i) * 128 + col],
                              W[(k0 + 2 * i + 1) * 128 + col]);
        out[c] = make_uint4(u[0], u[1], u[2], u[3]);
    }
}

// ---------- CSR build ----------
__global__ __launch_bounds__(256) void hist_kernel(
    const int* __restrict__ receivers, unsigned* __restrict__ cnt)
{
    int i = blockIdx.x * 256 + threadIdx.x;
    if (i < NE) atomicAdd(&cnt[receivers[i]], 1u);
}

// scan phase 1: per-block exclusive scan of 256 counts + block sum
__global__ __launch_bounds__(256) void scan1_kernel(
    const unsigned* __restrict__ cnt, unsigned* __restrict__ rowptr,
    unsigned* __restrict__ bsum)
{
    __shared__ unsigned sh[256];
    const int t = threadIdx.x;
    int i = blockIdx.x * 256 + t;
    unsigned c = (i < NN) ? cnt[i] : 0u;
    sh[t] = c;
    __syncthreads();
    unsigned incl = c;
    for (int off = 1; off < 256; off <<= 1) {
        unsigned v = (t >= off) ? sh[t - off] : 0u;
        __syncthreads();
        incl += v;
        sh[t] = incl;
        __syncthreads();
    }
    if (i < NN) rowptr[i] = incl - c;      // exclusive within block
    if (t == 255) bsum[blockIdx.x] = incl; // block total
}

// scan phase 2+3 fused: each block redundantly scans the block sums,
// picks its own offset, adds it.
__global__ __launch_bounds__(256) void scan3_kernel(
    unsigned* __restrict__ rowptr, const unsigned* __restrict__ bsum, int nb)
{
    __shared__ unsigned sh[256];
    __shared__ unsigned s_off;
    const int t = threadIdx.x;
    unsigned c = (t < nb) ? bsum[t] : 0u;
    sh[t] = c;
    __syncthreads();
    unsigned incl = c;
    for (int off = 1; off < 256; off <<= 1) {
        unsigned v = (t >= off) ? sh[t - off] : 0u;
        __syncthreads();
        incl += v;
        sh[t] = incl;
        __syncthreads();
    }
    if (t == 0) {
        s_off = (blockIdx.x > 0) ? sh[blockIdx.x - 1] : 0u;
        if (blockIdx.x == 0) rowptr[NN] = NE;
    }
    __syncthreads();
    int i = blockIdx.x * 256 + t;
    if (i < NN) rowptr[i] += s_off;
}

// scatter + inverse map jof: edge e lands at perm position jof[e]
__global__ __launch_bounds__(256) void scatter_kernel(
    const int* __restrict__ receivers, const unsigned* __restrict__ rowptr,
    unsigned* __restrict__ cnt2, unsigned* __restrict__ jof)
{
    int i = blockIdx.x * 256 + threadIdx.x;
    if (i >= NE) return;
    int r = receivers[i];
    unsigned pos = rowptr[r] + atomicAdd(&cnt2[r], 1u);
    jof[i] = pos;
}

// ---------- both node projections in one kernel ----------
// Sp/Rp layout (bf16, head-interleaved): node row = 64 uints (256 B);
// uint k = l15*4 + h holds cols (32h + l15, 32h + 16 + l15) as 2 bf16.
__global__ __launch_bounds__(256, 4) void proj_both(
    const float* __restrict__ X,
    const bf16x8* __restrict__ Wf0, const bf16x8* __restrict__ Wf1,
    const float* __restrict__ b0, const float* __restrict__ b1,
    int M, uint2* __restrict__ Sp, uint2* __restrict__ Rp)
{
    __shared__ __align__(16) char ldsA[32768];
    const int t = threadIdx.x;
    const int lane = t & 63;
    const int wid = t >> 6;
    const int wr = wid >> 1, wc = wid & 1;
    const int l15 = lane & 15, lgp = lane >> 4;
    const size_t rowbase = (size_t)blockIdx.x * 128;

    #pragma unroll
    for (int i = 0; i < 8; ++i) {
        int c = i * 256 + t;
        int row = c >> 4, cc = c & 15;
        size_t e = rowbase + row;
        uint4 p = make_uint4(0, 0, 0, 0);
        if (e < (size_t)M) {
            const float4* src = (const float4*)(X + e * F + cc * 8);
            float4 f0 = src[0], f1 = src[1];
            p.x = pack2_bf16(f0.x, f0.y);
            p.y = pack2_bf16(f0.z, f0.w);
            p.z = pack2_bf16(f1.x, f1.y);
            p.w = pack2_bf16(f1.z, f1.w);
        }
        unsigned byte = (unsigned)(row * 256 + cc * 16);
        byte ^= (unsigned)((row & 7) << 4);
        *(uint4*)(ldsA + byte) = p;
    }
    __syncthreads();

    #pragma unroll
    for (int pass = 0; pass < 2; ++pass) {
        const bf16x8* Wf = pass ? Wf1 : Wf0;
        const float* bias = pass ? b1 : b0;
        uint2* Y = pass ? Rp : Sp;

        f32x4 acc[4][4];
        #pragma unroll
        for (int n = 0; n < 4; ++n) {
            float bv = bias[wc * 64 + n * 16 + l15];
            #pragma unroll
            for (int m = 0; m < 4; ++m) {
                acc[m][n][0] = bv; acc[m][n][1] = bv;
                acc[m][n][2] = bv; acc[m][n][3] = bv;
            }
        }
        #pragma unroll
        for (int ks = 0; ks < 4; ++ks) {
            const int kb = ks * 64 + lgp * 16;
            bf16x8 af[4], bfr[4];
            #pragma unroll
            for (int m = 0; m < 4; ++m) {
                int row = wr * 64 + m * 16 + l15;
                unsigned byte = ((unsigned)(row * 256 + kb)) ^ ((row & 7) << 4);
                af[m] = *(const bf16x8*)(ldsA + byte);
            }
            #pragma unroll
            for (int n = 0; n < 4; ++n)
                bfr[n] = Wf[((wc * 4 + n) * 4 + ks) * 64 + lane];
            #pragma unroll
            for (int m = 0; m < 4; ++m)
                #pragma unroll
                for (int n = 0; n < 4; ++n)
                    acc[m][n] = __builtin_amdgcn_mfma_f32_16x16x32_bf16(
                        af[m], bfr[n], acc[m][n], 0, 0, 0);
        }
        // store: this thread's cols are heads wc*2 + {0,1}, col-class l15
        #pragma unroll
        for (int m = 0; m < 4; ++m)
            #pragma unroll
            for (int j = 0; j < 4; ++j) {
                int row = wr * 64 + m * 16 + lgp * 4 + j;
                size_t e = rowbase + row;
                if (e >= (size_t)M) continue;
                uint2 pk;
                pk.x = pack2_bf16(acc[m][0][j], acc[m][1][j]);
                pk.y = pack2_bf16(acc[m][2][j], acc[m][3][j]);
                Y[e * 32 + l15 * 2 + wc] = pk;   // uints k = l15*4 + wc*2 + {0,1}
            }
    }
}

// ---------- edge GEMM: BM=64, minimal tail, 8 blocks/CU ----------
// 4 waves/block, wave w owns rows w*16..w*16+15 across all 128 cols.
// EA row layout (bf16): uint k = l15*4 + h holds cols (32h+l15, 32h+16+l15).
__global__ __launch_bounds__(256, 8) void edge_gemm(
    const float* __restrict__ X, const bf16x8* __restrict__ Wf,
    const float* __restrict__ bias,
    const int* __restrict__ senders, const unsigned* __restrict__ jof,
    const uint4* __restrict__ Sp4, uint4* __restrict__ EAp)
{
    __shared__ __align__(16) char ldsA[16384];
    const int t = threadIdx.x;
    const int lane = t & 63;
    const int wid = t >> 6;
    const int l15 = lane & 15, lgp = lane >> 4;
    const size_t rowbase = (size_t)blockIdx.x * 64;

    // ---- stage A: 64 edge rows -> bf16, XOR-swizzled (16 KB) ----
    #pragma unroll
    for (int i = 0; i < 4; ++i) {
        int c = i * 256 + t;
        int row = c >> 4, cc = c & 15;
        const float4* src = (const float4*)(X + (rowbase + row) * F + cc * 8);
        float4 f0 = src[0], f1 = src[1];
        uint4 p;
        p.x = pack2_bf16(f0.x, f0.y);
        p.y = pack2_bf16(f0.z, f0.w);
        p.z = pack2_bf16(f1.x, f1.y);
        p.w = pack2_bf16(f1.z, f1.w);
        unsigned byte = (unsigned)(row * 256 + cc * 16);
        byte ^= (unsigned)((row & 7) << 4);
        *(uint4*)(ldsA + byte) = p;
    }

    f32x4 acc[8];
    #pragma unroll
    for (int n = 0; n < 8; ++n) {
        float bv = bias[n * 16 + l15];
        acc[n][0] = bv; acc[n][1] = bv; acc[n][2] = bv; acc[n][3] = bv;
    }
    __syncthreads();

    // ---- MFMA: A from LDS, B straight from L2-resident fragment buffer ----
    #pragma unroll
    for (int ks = 0; ks < 4; ++ks) {
        int arow = wid * 16 + l15;
        unsigned abyte = ((unsigned)(arow * 256 + ks * 64 + lgp * 16))
                         ^ ((arow & 7) << 4);
        bf16x8 af = *(const bf16x8*)(ldsA + abyte);
        #pragma unroll
        for (int n = 0; n < 8; ++n) {
            bf16x8 bfr = Wf[(n * 4 + ks) * 64 + lane];
            acc[n] = __builtin_amdgcn_mfma_f32_16x16x32_bf16(af, bfr, acc[n], 0, 0, 0);
        }
    }

    // ---- tail: 4 rows per thread (row = wid*16 + lgp*4 + j) ----
    #pragma unroll
    for (int j = 0; j < 4; ++j) {
        int row = wid * 16 + lgp * 4 + j;
        size_t e = rowbase + row;
        int snd = senders[e];          // 16-lane broadcast loads
        unsigned jj = jof[e];
        uint4 sv = Sp4[(size_t)snd * 16 + l15];
        unsigned uo[4];
        #pragma unroll
        for (int h = 0; h < 4; ++h) {
            unsigned sp = (h == 0) ? sv.x : (h == 1) ? sv.y : (h == 2) ? sv.z : sv.w;
            float elo = acc[2 * h][j]     + bf16lo_to_f32(sp);
            float ehi = acc[2 * h + 1][j] + bf16hi_to_f32(sp);
            uo[h] = pack2_bf16(elo, ehi);
        }
        EAp[(size_t)jj * 16 + l15] = make_uint4(uo[0], uo[1], uo[2], uo[3]);
    }
}

// ---------- fused logit + single-pass softmax + aggregate ----------
// One wave per receiver; unrolled x2 (two independent latency chains).
__global__ __launch_bounds__(256) void agg_kernel(
    const unsigned* __restrict__ rowptr,
    const uint4* __restrict__ Rp4,
    const float* __restrict__ attw, const float* __restrict__ attb,
    const unsigned* __restrict__ EA, float* __restrict__ out)
{
    const int lane = threadIdx.x & 63;
    const int r = blockIdx.x * 4 + (threadIdx.x >> 6);
    if (r >= NN) return;
    const unsigned start = rowptr[r], end = rowptr[r + 1];

    // EA uint k = lane: l15c = lane>>2, h = lane&3, cols (32h+l15c, +16)
    const int h    = lane & 3;
    const int l15c = lane >> 2;
    const int c0   = 32 * h + l15c;

    if (start == end) {
        out[(size_t)r * HD + c0]      = 0.f;
        out[(size_t)r * HD + c0 + 16] = 0.f;
        return;
    }

    uint4 rv4 = Rp4[(size_t)r * 16 + l15c];
    unsigned rp = (h == 0) ? rv4.x : (h == 1) ? rv4.y : (h == 2) ? rv4.z : rv4.w;
    const float rlo = bf16lo_to_f32(rp), rhi = bf16hi_to_f32(rp);
    const float aw0 = attw[l15c];
    const float aw1 = attw[l15c + 16];
    const float ab0 = attb[0];
    const unsigned* ea = EA + lane;

    float ax0 = 0.f, ay0 = 0.f, dn0 = 0.f;
    float ax1 = 0.f, ay1 = 0.f, dn1 = 0.f;
    unsigned j = start;
    for (; j + 2 <= end; j += 2) {
        unsigned p0 = ea[(size_t)j * 64];
        unsigned p1 = ea[(size_t)(j + 1) * 64];
        float e0l = bf16lo_to_f32(p0), e0h = bf16hi_to_f32(p0);
        float e1l = bf16lo_to_f32(p1), e1h = bf16hi_to_f32(p1);
        float t0 = mish_f(e0l + rlo) * aw0 + mish_f(e0h + rhi) * aw1;
        float t1 = mish_f(e1l + rlo) * aw0 + mish_f(e1h + rhi) * aw1;
        t0 += __shfl_xor(t0, 4);   t1 += __shfl_xor(t1, 4);
        t0 += __shfl_xor(t0, 8);   t1 += __shfl_xor(t1, 8);
        t0 += __shfl_xor(t0, 16);  t1 += __shfl_xor(t1, 16);
        t0 += __shfl_xor(t0, 32);  t1 += __shfl_xor(t1, 32);
        float w0 = __expf(t0 + ab0);
        float w1 = __expf(t1 + ab0);
        dn0 += w0;  ax0 += w0 * e0l;  ay0 += w0 * e0h;
        dn1 += w1;  ax1 += w1 * e1l;  ay1 += w1 * e1h;
    }
    if (j < end) {
        unsigned p0 = ea[(size_t)j * 64];
        float e0l = bf16lo_to_f32(p0), e0h = bf16hi_to_f32(p0);
        float t0 = mish_f(e0l + rlo) * aw0 + mish_f(e0h + rhi) * aw1;
        t0 += __shfl_xor(t0, 4);
        t0 += __shfl_xor(t0, 8);
        t0 += __shfl_xor(t0, 16);
        t0 += __shfl_xor(t0, 32);
        float w0 = __expf(t0 + ab0);
        dn0 += w0;  ax0 += w0 * e0l;  ay0 += w0 * e0h;
    }
    float rd = 1.f / (dn0 + dn1);
    out[(size_t)r * HD + c0]      = (ax0 + ax1) * rd;
    out[(size_t)r * HD + c0 + 16] = (ay0 + ay1) * rd;
}

// ---------- host ----------
extern "C" void kernel_launch(void* const* d_in, const int* in_sizes, int n_in,
                              void* d_out, int out_size, void* d_ws, size_t ws_size,
                              hipStream_t stream) {
    const float* nodes = (const float*)d_in[0];
    const float* edges = (const float*)d_in[1];
    const float* Ws_k  = (const float*)d_in[2];
    const float* Ws_b  = (const float*)d_in[3];
    const float* Wr_k  = (const float*)d_in[4];
    const float* Wr_b  = (const float*)d_in[5];
    const float* We_k  = (const float*)d_in[6];
    const float* We_b  = (const float*)d_in[7];
    const float* attw  = (const float*)d_in[8];
    const float* attb  = (const float*)d_in[9];
    const int* senders   = (const int*)d_in[10];
    const int* receivers = (const int*)d_in[11];
    float* out = (float*)d_out;

    char* ws = (char*)d_ws;
    const size_t CNT_OFF  = 0;            // 200,000
    const size_t CNT2_OFF = 200000;       // 200,000
    const size_t RP_OFF   = 400000;       // 200,004
    const size_t BS_OFF   = 600004;       // 1,024 (bsum)
    const size_t JOF_OFF  = 700000;       // 3,200,000 -> ends 3,900,000
    const size_t WF_OFF   = 3900000;      // 98,304    -> ends 3,998,304
    const size_t SP_OFF   = 4000000;      // 12,800,000 (bf16) -> 16.8e6
    const size_t RPP_OFF  = 16800000;     // 12,800,000 -> 29.6e6
    const size_t EA_OFF   = 29600000;     // 204,800,000 -> 234.4e6

    unsigned* cnt    = (unsigned*)(ws + CNT_OFF);
    unsigned* cnt2   = (unsigned*)(ws + CNT2_OFF);
    unsigned* rowptr = (unsigned*)(ws + RP_OFF);
    unsigned* bsum   = (unsigned*)(ws + BS_OFF);
    unsigned* jof    = (unsigned*)(ws + JOF_OFF);
    uint4*    Wf     = (uint4*)(ws + WF_OFF);
    uint2*    Sp     = (uint2*)(ws + SP_OFF);
    uint2*    Rp     = (uint2*)(ws + RPP_OFF);
    unsigned* EA     = (unsigned*)(ws + EA_OFF);
    (void)ws_size;

    const int NB = (NN + 255) / 256;   // 196 scan blocks

    // weights -> bf16 fragment order; extra blocks zero cnt/cnt2
    prep_w<<<3 + 98, 256, 0, stream>>>(Ws_k, Wr_k, We_k, Wf, (uint4*)(ws + CNT_OFF));

    // CSR build (rowptr + inverse perm map jof), multi-block scan
    hist_kernel<<<(NE + 255) / 256, 256, 0, stream>>>(receivers, cnt);
    scan1_kernel<<<NB, 256, 0, stream>>>(cnt, rowptr, bsum);
    scan3_kernel<<<NB, 256, 0, stream>>>(rowptr, bsum, NB);
    scatter_kernel<<<(NE + 255) / 256, 256, 0, stream>>>(receivers, rowptr, cnt2, jof);

    // both node projections (bf16 head-interleaved packed output)
    proj_both<<<(NN + 127) / 128, 256, 0, stream>>>(
        nodes, (const bf16x8*)Wf, (const bf16x8*)(Wf + 2048),
        Ws_b, Wr_b, NN, Sp, Rp);

    // edge GEMM: EA written at perm positions (no logits, no R gather)
    edge_gemm<<<NE / 64, 256, 0, stream>>>(
        edges, (const bf16x8*)(Wf + 4096), We_b,
        senders, jof, (const uint4*)Sp, (uint4*)EA);

    // fused logit + single-pass softmax + aggregation (one wave/receiver)
    agg_kernel<<<(NN + 3) / 4, 256, 0, stream>>>(
        rowptr, (const uint4*)Rp, attw, attb, EA, out);
}

// Round 13
// 375.794 us; speedup vs baseline: 1.0484x; 1.0473x over previous
//
#include <hip/hip_runtime.h>
#include <hip/hip_bf16.h>

#define NN 50000
#define NE 800000
#define F 128     // input feature dim (= K)
#define HD 128    // output dim = H*DH (= N)
#define H 4

typedef __attribute__((ext_vector_type(4))) float f32x4;
typedef __attribute__((ext_vector_type(8))) __bf16 bf16x8;
typedef __attribute__((ext_vector_type(2))) __bf16 bf16x2;

// ---------- helpers ----------

// mish(x) = x * tanh(softplus(x)) = x * (u-1)/(u+1), u = (1+e^x)^2
__device__ __forceinline__ float mish_f(float x) {
    if (x > 30.f) return x;
    float t = __expf(x);
    float u = 1.f + t;
    u = u * u;
    return x * (u - 1.f) * __builtin_amdgcn_rcpf(u + 1.f);
}

// packed f32x2 -> bf16x2 (compiler emits v_cvt_pk_bf16_f32, RNE)
__device__ __forceinline__ unsigned pack2_bf16(float a, float b) {
    bf16x2 v;
    v.x = (__bf16)a;
    v.y = (__bf16)b;
    return __builtin_bit_cast(unsigned, v);
}
__device__ __forceinline__ float bf16lo_to_f32(unsigned p) {
    return __uint_as_float((p & 0xFFFFu) << 16);
}
__device__ __forceinline__ float bf16hi_to_f32(unsigned p) {
    return __uint_as_float(p & 0xFFFF0000u);
}

// ---------- prep: W -> bf16 fragment-ordered; extra blocks zero cnt/cnt2 ----------
__global__ __launch_bounds__(256) void prep_w(
    const float* __restrict__ W0, const float* __restrict__ W1,
    const float* __restrict__ W2, uint4* __restrict__ O,
    uint4* __restrict__ zero_dst)   // 400,000 B = 25,000 uint4
{
    int b = blockIdx.x;
    if (b >= 3) {
        int i = (b - 3) * 256 + threadIdx.x;
        if (i < 25000) zero_dst[i] = make_uint4(0, 0, 0, 0);
        return;
    }
    const float* W = (b == 0) ? W0 : (b == 1) ? W1 : W2;
    uint4* out = O + b * 2048;
    for (int c = threadIdx.x; c < 2048; c += 256) {
        int fn = c >> 8, ks = (c >> 6) & 3, lane = c & 63;
        int lgp = lane >> 4, l15 = lane & 15;
        int col = fn * 16 + l15, k0 = ks * 32 + lgp * 8;
        unsigned u[4];
        #pragma unroll
        for (int i = 0; i < 4; ++i)
            u[i] = pack2_bf16(W[(k0 + 2 * i) * 128 + col],
                              W[(k0 + 2 * i + 1) * 128 + col]);
        out[c] = make_uint4(u[0], u[1], u[2], u[3]);
    }
}

// ---------- CSR build ----------
__global__ __launch_bounds__(256) void hist_kernel(
    const int* __restrict__ receivers, unsigned* __restrict__ cnt)
{
    int i = blockIdx.x * 256 + threadIdx.x;
    if (i < NE) atomicAdd(&cnt[receivers[i]], 1u);
}

// scan phase 1: per-block exclusive scan of 256 counts + block sum
__global__ __launch_bounds__(256) void scan1_kernel(
    const unsigned* __restrict__ cnt, unsigned* __restrict__ rowptr,
    unsigned* __restrict__ bsum)
{
    __shared__ unsigned sh[256];
    const int t = threadIdx.x;
    int i = blockIdx.x * 256 + t;
    unsigned c = (i < NN) ? cnt[i] : 0u;
    sh[t] = c;
    __syncthreads();
    unsigned incl = c;
    for (int off = 1; off < 256; off <<= 1) {
        unsigned v = (t >= off) ? sh[t - off] : 0u;
        __syncthreads();
        incl += v;
        sh[t] = incl;
        __syncthreads();
    }
    if (i < NN) rowptr[i] = incl - c;      // exclusive within block
    if (t == 255) bsum[blockIdx.x] = incl; // block total
}

// scan phase 2+3 fused: each block redundantly scans the block sums,
// picks its own offset, adds it.
__global__ __launch_bounds__(256) void scan3_kernel(
    unsigned* __restrict__ rowptr, const unsigned* __restrict__ bsum, int nb)
{
    __shared__ unsigned sh[256];
    __shared__ unsigned s_off;
    const int t = threadIdx.x;
    unsigned c = (t < nb) ? bsum[t] : 0u;
    sh[t] = c;
    __syncthreads();
    unsigned incl = c;
    for (int off = 1; off < 256; off <<= 1) {
        unsigned v = (t >= off) ? sh[t - off] : 0u;
        __syncthreads();
        incl += v;
        sh[t] = incl;
        __syncthreads();
    }
    if (t == 0) {
        s_off = (blockIdx.x > 0) ? sh[blockIdx.x - 1] : 0u;
        if (blockIdx.x == 0) rowptr[NN] = NE;
    }
    __syncthreads();
    int i = blockIdx.x * 256 + t;
    if (i < NN) rowptr[i] += s_off;
}

// scatter + inverse map jof: edge e lands at perm position jof[e]
__global__ __launch_bounds__(256) void scatter_kernel(
    const int* __restrict__ receivers, const unsigned* __restrict__ rowptr,
    unsigned* __restrict__ cnt2, unsigned* __restrict__ jof)
{
    int i = blockIdx.x * 256 + threadIdx.x;
    if (i >= NE) return;
    int r = receivers[i];
    unsigned pos = rowptr[r] + atomicAdd(&cnt2[r], 1u);
    jof[i] = pos;
}

// ---------- both node projections in one kernel ----------
// Sp/Rp layout (bf16, head-interleaved): node row = 64 uints (256 B);
// uint k = l15*4 + h holds cols (32h + l15, 32h + 16 + l15) as 2 bf16.
__global__ __launch_bounds__(256, 4) void proj_both(
    const float* __restrict__ X,
    const bf16x8* __restrict__ Wf0, const bf16x8* __restrict__ Wf1,
    const float* __restrict__ b0, const float* __restrict__ b1,
    int M, uint2* __restrict__ Sp, uint2* __restrict__ Rp)
{
    __shared__ __align__(16) char ldsA[32768];
    const int t = threadIdx.x;
    const int lane = t & 63;
    const int wid = t >> 6;
    const int wr = wid >> 1, wc = wid & 1;
    const int l15 = lane & 15, lgp = lane >> 4;
    const size_t rowbase = (size_t)blockIdx.x * 128;

    #pragma unroll
    for (int i = 0; i < 8; ++i) {
        int c = i * 256 + t;
        int row = c >> 4, cc = c & 15;
        size_t e = rowbase + row;
        uint4 p = make_uint4(0, 0, 0, 0);
        if (e < (size_t)M) {
            const float4* src = (const float4*)(X + e * F + cc * 8);
            float4 f0 = src[0], f1 = src[1];
            p.x = pack2_bf16(f0.x, f0.y);
            p.y = pack2_bf16(f0.z, f0.w);
            p.z = pack2_bf16(f1.x, f1.y);
            p.w = pack2_bf16(f1.z, f1.w);
        }
        unsigned byte = (unsigned)(row * 256 + cc * 16);
        byte ^= (unsigned)((row & 7) << 4);
        *(uint4*)(ldsA + byte) = p;
    }
    __syncthreads();

    #pragma unroll
    for (int pass = 0; pass < 2; ++pass) {
        const bf16x8* Wf = pass ? Wf1 : Wf0;
        const float* bias = pass ? b1 : b0;
        uint2* Y = pass ? Rp : Sp;

        f32x4 acc[4][4];
        #pragma unroll
        for (int n = 0; n < 4; ++n) {
            float bv = bias[wc * 64 + n * 16 + l15];
            #pragma unroll
            for (int m = 0; m < 4; ++m) {
                acc[m][n][0] = bv; acc[m][n][1] = bv;
                acc[m][n][2] = bv; acc[m][n][3] = bv;
            }
        }
        #pragma unroll
        for (int ks = 0; ks < 4; ++ks) {
            const int kb = ks * 64 + lgp * 16;
            bf16x8 af[4], bfr[4];
            #pragma unroll
            for (int m = 0; m < 4; ++m) {
                int row = wr * 64 + m * 16 + l15;
                unsigned byte = ((unsigned)(row * 256 + kb)) ^ ((row & 7) << 4);
                af[m] = *(const bf16x8*)(ldsA + byte);
            }
            #pragma unroll
            for (int n = 0; n < 4; ++n)
                bfr[n] = Wf[((wc * 4 + n) * 4 + ks) * 64 + lane];
            #pragma unroll
            for (int m = 0; m < 4; ++m)
                #pragma unroll
                for (int n = 0; n < 4; ++n)
                    acc[m][n] = __builtin_amdgcn_mfma_f32_16x16x32_bf16(
                        af[m], bfr[n], acc[m][n], 0, 0, 0);
        }
        // store: this thread's cols are heads wc*2 + {0,1}, col-class l15
        #pragma unroll
        for (int m = 0; m < 4; ++m)
            #pragma unroll
            for (int j = 0; j < 4; ++j) {
                int row = wr * 64 + m * 16 + lgp * 4 + j;
                size_t e = rowbase + row;
                if (e >= (size_t)M) continue;
                uint2 pk;
                pk.x = pack2_bf16(acc[m][0][j], acc[m][1][j]);
                pk.y = pack2_bf16(acc[m][2][j], acc[m][3][j]);
                Y[e * 32 + l15 * 2 + wc] = pk;   // uints k = l15*4 + wc*2 + {0,1}
            }
    }
}

// ---------- edge GEMM: BM=64, NO LDS, NO barriers ----------
// 4 waves/block, wave w owns rows w*16..w*16+15 across all 128 cols.
// A-fragments loaded DIRECTLY from global (lane(l15,lgp) = row l15,
// k=lgp*8..+7 — matches MFMA A layout), packed to bf16 in registers.
// Waves are fully independent -> latency of Sp gather / EA scatter hides
// under other waves' streams.
__global__ __launch_bounds__(256, 8) void edge_gemm(
    const float* __restrict__ X, const bf16x8* __restrict__ Wf,
    const float* __restrict__ bias,
    const int* __restrict__ senders, const unsigned* __restrict__ jof,
    const uint4* __restrict__ Sp4, uint4* __restrict__ EAp)
{
    const int t = threadIdx.x;
    const int lane = t & 63;
    const int wid = t >> 6;
    const int l15 = lane & 15, lgp = lane >> 4;
    const size_t rowbase = (size_t)blockIdx.x * 64;
    const float* aptr = X + (rowbase + wid * 16 + l15) * F;

    f32x4 acc[8];
    #pragma unroll
    for (int n = 0; n < 8; ++n) {
        float bv = bias[n * 16 + l15];
        acc[n][0] = bv; acc[n][1] = bv; acc[n][2] = bv; acc[n][3] = bv;
    }

    #pragma unroll
    for (int ks = 0; ks < 4; ++ks) {
        const float4* ap = (const float4*)(aptr + ks * 32 + lgp * 8);
        float4 a0 = ap[0], a1 = ap[1];
        uint4 pu;
        pu.x = pack2_bf16(a0.x, a0.y);
        pu.y = pack2_bf16(a0.z, a0.w);
        pu.z = pack2_bf16(a1.x, a1.y);
        pu.w = pack2_bf16(a1.z, a1.w);
        bf16x8 af = __builtin_bit_cast(bf16x8, pu);
        #pragma unroll
        for (int n = 0; n < 8; ++n) {
            bf16x8 bfr = Wf[(n * 4 + ks) * 64 + lane];
            acc[n] = __builtin_amdgcn_mfma_f32_16x16x32_bf16(af, bfr, acc[n], 0, 0, 0);
        }
    }

    // ---- tail: 4 rows per thread (row = wid*16 + lgp*4 + j) ----
    #pragma unroll
    for (int j = 0; j < 4; ++j) {
        int row = wid * 16 + lgp * 4 + j;
        size_t e = rowbase + row;
        int snd = senders[e];          // 16-lane broadcast loads
        unsigned jj = jof[e];
        uint4 sv = Sp4[(size_t)snd * 16 + l15];
        unsigned uo[4];
        #pragma unroll
        for (int h = 0; h < 4; ++h) {
            unsigned sp = (h == 0) ? sv.x : (h == 1) ? sv.y : (h == 2) ? sv.z : sv.w;
            float elo = acc[2 * h][j]     + bf16lo_to_f32(sp);
            float ehi = acc[2 * h + 1][j] + bf16hi_to_f32(sp);
            uo[h] = pack2_bf16(elo, ehi);
        }
        EAp[(size_t)jj * 16 + l15] = make_uint4(uo[0], uo[1], uo[2], uo[3]);
    }
}

// ---------- fused logit + single-pass softmax + aggregate ----------
// One wave per receiver; unrolled x2 (two independent latency chains).
__global__ __launch_bounds__(256) void agg_kernel(
    const unsigned* __restrict__ rowptr,
    const uint4* __restrict__ Rp4,
    const float* __restrict__ attw, const float* __restrict__ attb,
    const unsigned* __restrict__ EA, float* __restrict__ out)
{
    const int lane = threadIdx.x & 63;
    const int r = blockIdx.x * 4 + (threadIdx.x >> 6);
    if (r >= NN) return;
    const unsigned start = rowptr[r], end = rowptr[r + 1];

    // EA uint k = lane: l15c = lane>>2, h = lane&3, cols (32h+l15c, +16)
    const int h    = lane & 3;
    const int l15c = lane >> 2;
    const int c0   = 32 * h + l15c;

    if (start == end) {
        out[(size_t)r * HD + c0]      = 0.f;
        out[(size_t)r * HD + c0 + 16] = 0.f;
        return;
    }

    uint4 rv4 = Rp4[(size_t)r * 16 + l15c];
    unsigned rp = (h == 0) ? rv4.x : (h == 1) ? rv4.y : (h == 2) ? rv4.z : rv4.w;
    const float rlo = bf16lo_to_f32(rp), rhi = bf16hi_to_f32(rp);
    const float aw0 = attw[l15c];
    const float aw1 = attw[l15c + 16];
    const float ab0 = attb[0];
    const unsigned* ea = EA + lane;

    float ax0 = 0.f, ay0 = 0.f, dn0 = 0.f;
    float ax1 = 0.f, ay1 = 0.f, dn1 = 0.f;
    unsigned j = start;
    for (; j + 2 <= end; j += 2) {
        unsigned p0 = ea[(size_t)j * 64];
        unsigned p1 = ea[(size_t)(j + 1) * 64];
        float e0l = bf16lo_to_f32(p0), e0h = bf16hi_to_f32(p0);
        float e1l = bf16lo_to_f32(p1), e1h = bf16hi_to_f32(p1);
        float t0 = mish_f(e0l + rlo) * aw0 + mish_f(e0h + rhi) * aw1;
        float t1 = mish_f(e1l + rlo) * aw0 + mish_f(e1h + rhi) * aw1;
        t0 += __shfl_xor(t0, 4);   t1 += __shfl_xor(t1, 4);
        t0 += __shfl_xor(t0, 8);   t1 += __shfl_xor(t1, 8);
        t0 += __shfl_xor(t0, 16);  t1 += __shfl_xor(t1, 16);
        t0 += __shfl_xor(t0, 32);  t1 += __shfl_xor(t1, 32);
        float w0 = __expf(t0 + ab0);
        float w1 = __expf(t1 + ab0);
        dn0 += w0;  ax0 += w0 * e0l;  ay0 += w0 * e0h;
        dn1 += w1;  ax1 += w1 * e1l;  ay1 += w1 * e1h;
    }
    if (j < end) {
        unsigned p0 = ea[(size_t)j * 64];
        float e0l = bf16lo_to_f32(p0), e0h = bf16hi_to_f32(p0);
        float t0 = mish_f(e0l + rlo) * aw0 + mish_f(e0h + rhi) * aw1;
        t0 += __shfl_xor(t0, 4);
        t0 += __shfl_xor(t0, 8);
        t0 += __shfl_xor(t0, 16);
        t0 += __shfl_xor(t0, 32);
        float w0 = __expf(t0 + ab0);
        dn0 += w0;  ax0 += w0 * e0l;  ay0 += w0 * e0h;
    }
    float rd = 1.f / (dn0 + dn1);
    out[(size_t)r * HD + c0]      = (ax0 + ax1) * rd;
    out[(size_t)r * HD + c0 + 16] = (ay0 + ay1) * rd;
}

// ---------- host ----------
extern "C" void kernel_launch(void* const* d_in, const int* in_sizes, int n_in,
                              void* d_out, int out_size, void* d_ws, size_t ws_size,
                              hipStream_t stream) {
    const float* nodes = (const float*)d_in[0];
    const float* edges = (const float*)d_in[1];
    const float* Ws_k  = (const float*)d_in[2];
    const float* Ws_b  = (const float*)d_in[3];
    const float* Wr_k  = (const float*)d_in[4];
    const float* Wr_b  = (const float*)d_in[5];
    const float* We_k  = (const float*)d_in[6];
    const float* We_b  = (const float*)d_in[7];
    const float* attw  = (const float*)d_in[8];
    const float* attb  = (const float*)d_in[9];
    const int* senders   = (const int*)d_in[10];
    const int* receivers = (const int*)d_in[11];
    float* out = (float*)d_out;

    char* ws = (char*)d_ws;
    const size_t CNT_OFF  = 0;            // 200,000
    const size_t CNT2_OFF = 200000;       // 200,000
    const size_t RP_OFF   = 400000;       // 200,004
    const size_t BS_OFF   = 600004;       // 1,024 (bsum)
    const size_t JOF_OFF  = 700000;       // 3,200,000 -> ends 3,900,000
    const size_t WF_OFF   = 3900000;      // 98,304    -> ends 3,998,304
    const size_t SP_OFF   = 4000000;      // 12,800,000 (bf16) -> 16.8e6
    const size_t RPP_OFF  = 16800000;     // 12,800,000 -> 29.6e6
    const size_t EA_OFF   = 29600000;     // 204,800,000 -> 234.4e6

    unsigned* cnt    = (unsigned*)(ws + CNT_OFF);
    unsigned* cnt2   = (unsigned*)(ws + CNT2_OFF);
    unsigned* rowptr = (unsigned*)(ws + RP_OFF);
    unsigned* bsum   = (unsigned*)(ws + BS_OFF);
    unsigned* jof    = (unsigned*)(ws + JOF_OFF);
    uint4*    Wf     = (uint4*)(ws + WF_OFF);
    uint2*    Sp     = (uint2*)(ws + SP_OFF);
    uint2*    Rp     = (uint2*)(ws + RPP_OFF);
    unsigned* EA     = (unsigned*)(ws + EA_OFF);
    (void)ws_size;

    const int NB = (NN + 255) / 256;   // 196 scan blocks

    // weights -> bf16 fragment order; extra blocks zero cnt/cnt2
    prep_w<<<3 + 98, 256, 0, stream>>>(Ws_k, Wr_k, We_k, Wf, (uint4*)(ws + CNT_OFF));

    // CSR build (rowptr + inverse perm map jof), multi-block scan
    hist_kernel<<<(NE + 255) / 256, 256, 0, stream>>>(receivers, cnt);
    scan1_kernel<<<NB, 256, 0, stream>>>(cnt, rowptr, bsum);
    scan3_kernel<<<NB, 256, 0, stream>>>(rowptr, bsum, NB);
    scatter_kernel<<<(NE + 255) / 256, 256, 0, stream>>>(receivers, rowptr, cnt2, jof);

    // both node projections (bf16 head-interleaved packed output)
    proj_both<<<(NN + 127) / 128, 256, 0, stream>>>(
        nodes, (const bf16x8*)Wf, (const bf16x8*)(Wf + 2048),
        Ws_b, Wr_b, NN, Sp, Rp);

    // edge GEMM: EA written at perm positions (no LDS, no barriers)
    edge_gemm<<<NE / 64, 256, 0, stream>>>(
        edges, (const bf16x8*)(Wf + 4096), We_b,
        senders, jof, (const uint4*)Sp, (uint4*)EA);

    // fused logit + single-pass softmax + aggregation (one wave/receiver)
    agg_kernel<<<(NN + 3) / 4, 256, 0, stream>>>(
        rowptr, (const uint4*)Rp, attw, attb, EA, out);
}

// Round 14
// 371.133 us; speedup vs baseline: 1.0615x; 1.0126x over previous
//
#include <hip/hip_runtime.h>
#include <hip/hip_bf16.h>

#define NN 50000
#define NE 800000
#define F 128     // input feature dim (= K)
#define HD 128    // output dim = H*DH (= N)
#define H 4

typedef __attribute__((ext_vector_type(4))) float f32x4;
typedef __attribute__((ext_vector_type(8))) __bf16 bf16x8;
typedef __attribute__((ext_vector_type(2))) __bf16 bf16x2;

// ---------- helpers ----------

// mish(x) = x * tanh(softplus(x)) = x * (u-1)/(u+1), u = (1+e^x)^2
__device__ __forceinline__ float mish_f(float x) {
    if (x > 30.f) return x;
    float t = __expf(x);
    float u = 1.f + t;
    u = u * u;
    return x * (u - 1.f) * __builtin_amdgcn_rcpf(u + 1.f);
}

// packed f32x2 -> bf16x2 (compiler emits v_cvt_pk_bf16_f32, RNE)
__device__ __forceinline__ unsigned pack2_bf16(float a, float b) {
    bf16x2 v;
    v.x = (__bf16)a;
    v.y = (__bf16)b;
    return __builtin_bit_cast(unsigned, v);
}
__device__ __forceinline__ float bf16lo_to_f32(unsigned p) {
    return __uint_as_float((p & 0xFFFFu) << 16);
}
__device__ __forceinline__ float bf16hi_to_f32(unsigned p) {
    return __uint_as_float(p & 0xFFFF0000u);
}

// DPP-based add: v += lane-permuted v within a row of 16 (VALU, no DS)
#define DPP_ADD(v, ctrl)                                                     \
    (v) += __int_as_float(__builtin_amdgcn_update_dpp(                       \
        0, __float_as_int(v), (ctrl), 0xf, 0xf, true))

// ---------- prep: W -> bf16 fragment-ordered; extra blocks zero cnt/cnt2 ----------
__global__ __launch_bounds__(256) void prep_w(
    const float* __restrict__ W0, const float* __restrict__ W1,
    const float* __restrict__ W2, uint4* __restrict__ O,
    uint4* __restrict__ zero_dst)   // 400,000 B = 25,000 uint4
{
    int b = blockIdx.x;
    if (b >= 3) {
        int i = (b - 3) * 256 + threadIdx.x;
        if (i < 25000) zero_dst[i] = make_uint4(0, 0, 0, 0);
        return;
    }
    const float* W = (b == 0) ? W0 : (b == 1) ? W1 : W2;
    uint4* out = O + b * 2048;
    for (int c = threadIdx.x; c < 2048; c += 256) {
        int fn = c >> 8, ks = (c >> 6) & 3, lane = c & 63;
        int lgp = lane >> 4, l15 = lane & 15;
        int col = fn * 16 + l15, k0 = ks * 32 + lgp * 8;
        unsigned u[4];
        #pragma unroll
        for (int i = 0; i < 4; ++i)
            u[i] = pack2_bf16(W[(k0 + 2 * i) * 128 + col],
                              W[(k0 + 2 * i + 1) * 128 + col]);
        out[c] = make_uint4(u[0], u[1], u[2], u[3]);
    }
}

// ---------- CSR build ----------
__global__ __launch_bounds__(256) void hist_kernel(
    const int* __restrict__ receivers, unsigned* __restrict__ cnt)
{
    int i = blockIdx.x * 256 + threadIdx.x;
    if (i < NE) atomicAdd(&cnt[receivers[i]], 1u);
}

// scan phase 1: per-block exclusive scan of 256 counts + block sum
__global__ __launch_bounds__(256) void scan1_kernel(
    const unsigned* __restrict__ cnt, unsigned* __restrict__ rowptr,
    unsigned* __restrict__ bsum)
{
    __shared__ unsigned sh[256];
    const int t = threadIdx.x;
    int i = blockIdx.x * 256 + t;
    unsigned c = (i < NN) ? cnt[i] : 0u;
    sh[t] = c;
    __syncthreads();
    unsigned incl = c;
    for (int off = 1; off < 256; off <<= 1) {
        unsigned v = (t >= off) ? sh[t - off] : 0u;
        __syncthreads();
        incl += v;
        sh[t] = incl;
        __syncthreads();
    }
    if (i < NN) rowptr[i] = incl - c;      // exclusive within block
    if (t == 255) bsum[blockIdx.x] = incl; // block total
}

// scan phase 2+3 fused: each block redundantly scans the block sums,
// picks its own offset, adds it.
__global__ __launch_bounds__(256) void scan3_kernel(
    unsigned* __restrict__ rowptr, const unsigned* __restrict__ bsum, int nb)
{
    __shared__ unsigned sh[256];
    __shared__ unsigned s_off;
    const int t = threadIdx.x;
    unsigned c = (t < nb) ? bsum[t] : 0u;
    sh[t] = c;
    __syncthreads();
    unsigned incl = c;
    for (int off = 1; off < 256; off <<= 1) {
        unsigned v = (t >= off) ? sh[t - off] : 0u;
        __syncthreads();
        incl += v;
        sh[t] = incl;
        __syncthreads();
    }
    if (t == 0) {
        s_off = (blockIdx.x > 0) ? sh[blockIdx.x - 1] : 0u;
        if (blockIdx.x == 0) rowptr[NN] = NE;
    }
    __syncthreads();
    int i = blockIdx.x * 256 + t;
    if (i < NN) rowptr[i] += s_off;
}

// scatter + inverse map jof: edge e lands at perm position jof[e]
__global__ __launch_bounds__(256) void scatter_kernel(
    const int* __restrict__ receivers, const unsigned* __restrict__ rowptr,
    unsigned* __restrict__ cnt2, unsigned* __restrict__ jof)
{
    int i = blockIdx.x * 256 + threadIdx.x;
    if (i >= NE) return;
    int r = receivers[i];
    unsigned pos = rowptr[r] + atomicAdd(&cnt2[r], 1u);
    jof[i] = pos;
}

// ---------- both node projections in one kernel ----------
// Sp/Rp layout (bf16, head-interleaved): node row = 64 uints (256 B);
// uint k = l15*4 + h holds cols (32h + l15, 32h + 16 + l15) as 2 bf16.
__global__ __launch_bounds__(256, 4) void proj_both(
    const float* __restrict__ X,
    const bf16x8* __restrict__ Wf0, const bf16x8* __restrict__ Wf1,
    const float* __restrict__ b0, const float* __restrict__ b1,
    int M, uint2* __restrict__ Sp, uint2* __restrict__ Rp)
{
    __shared__ __align__(16) char ldsA[32768];
    const int t = threadIdx.x;
    const int lane = t & 63;
    const int wid = t >> 6;
    const int wr = wid >> 1, wc = wid & 1;
    const int l15 = lane & 15, lgp = lane >> 4;
    const size_t rowbase = (size_t)blockIdx.x * 128;

    #pragma unroll
    for (int i = 0; i < 8; ++i) {
        int c = i * 256 + t;
        int row = c >> 4, cc = c & 15;
        size_t e = rowbase + row;
        uint4 p = make_uint4(0, 0, 0, 0);
        if (e < (size_t)M) {
            const float4* src = (const float4*)(X + e * F + cc * 8);
            float4 f0 = src[0], f1 = src[1];
            p.x = pack2_bf16(f0.x, f0.y);
            p.y = pack2_bf16(f0.z, f0.w);
            p.z = pack2_bf16(f1.x, f1.y);
            p.w = pack2_bf16(f1.z, f1.w);
        }
        unsigned byte = (unsigned)(row * 256 + cc * 16);
        byte ^= (unsigned)((row & 7) << 4);
        *(uint4*)(ldsA + byte) = p;
    }
    __syncthreads();

    #pragma unroll
    for (int pass = 0; pass < 2; ++pass) {
        const bf16x8* Wf = pass ? Wf1 : Wf0;
        const float* bias = pass ? b1 : b0;
        uint2* Y = pass ? Rp : Sp;

        f32x4 acc[4][4];
        #pragma unroll
        for (int n = 0; n < 4; ++n) {
            float bv = bias[wc * 64 + n * 16 + l15];
            #pragma unroll
            for (int m = 0; m < 4; ++m) {
                acc[m][n][0] = bv; acc[m][n][1] = bv;
                acc[m][n][2] = bv; acc[m][n][3] = bv;
            }
        }
        #pragma unroll
        for (int ks = 0; ks < 4; ++ks) {
            const int kb = ks * 64 + lgp * 16;
            bf16x8 af[4], bfr[4];
            #pragma unroll
            for (int m = 0; m < 4; ++m) {
                int row = wr * 64 + m * 16 + l15;
                unsigned byte = ((unsigned)(row * 256 + kb)) ^ ((row & 7) << 4);
                af[m] = *(const bf16x8*)(ldsA + byte);
            }
            #pragma unroll
            for (int n = 0; n < 4; ++n)
                bfr[n] = Wf[((wc * 4 + n) * 4 + ks) * 64 + lane];
            #pragma unroll
            for (int m = 0; m < 4; ++m)
                #pragma unroll
                for (int n = 0; n < 4; ++n)
                    acc[m][n] = __builtin_amdgcn_mfma_f32_16x16x32_bf16(
                        af[m], bfr[n], acc[m][n], 0, 0, 0);
        }
        // store: this thread's cols are heads wc*2 + {0,1}, col-class l15
        #pragma unroll
        for (int m = 0; m < 4; ++m)
            #pragma unroll
            for (int j = 0; j < 4; ++j) {
                int row = wr * 64 + m * 16 + lgp * 4 + j;
                size_t e = rowbase + row;
                if (e >= (size_t)M) continue;
                uint2 pk;
                pk.x = pack2_bf16(acc[m][0][j], acc[m][1][j]);
                pk.y = pack2_bf16(acc[m][2][j], acc[m][3][j]);
                Y[e * 32 + l15 * 2 + wc] = pk;   // uints k = l15*4 + wc*2 + {0,1}
            }
    }
}

// ---------- edge GEMM: BM=64, NO LDS, NO barriers ----------
__global__ __launch_bounds__(256, 8) void edge_gemm(
    const float* __restrict__ X, const bf16x8* __restrict__ Wf,
    const float* __restrict__ bias,
    const int* __restrict__ senders, const unsigned* __restrict__ jof,
    const uint4* __restrict__ Sp4, uint4* __restrict__ EAp)
{
    const int t = threadIdx.x;
    const int lane = t & 63;
    const int wid = t >> 6;
    const int l15 = lane & 15, lgp = lane >> 4;
    const size_t rowbase = (size_t)blockIdx.x * 64;
    const float* aptr = X + (rowbase + wid * 16 + l15) * F;

    f32x4 acc[8];
    #pragma unroll
    for (int n = 0; n < 8; ++n) {
        float bv = bias[n * 16 + l15];
        acc[n][0] = bv; acc[n][1] = bv; acc[n][2] = bv; acc[n][3] = bv;
    }

    #pragma unroll
    for (int ks = 0; ks < 4; ++ks) {
        const float4* ap = (const float4*)(aptr + ks * 32 + lgp * 8);
        float4 a0 = ap[0], a1 = ap[1];
        uint4 pu;
        pu.x = pack2_bf16(a0.x, a0.y);
        pu.y = pack2_bf16(a0.z, a0.w);
        pu.z = pack2_bf16(a1.x, a1.y);
        pu.w = pack2_bf16(a1.z, a1.w);
        bf16x8 af = __builtin_bit_cast(bf16x8, pu);
        #pragma unroll
        for (int n = 0; n < 8; ++n) {
            bf16x8 bfr = Wf[(n * 4 + ks) * 64 + lane];
            acc[n] = __builtin_amdgcn_mfma_f32_16x16x32_bf16(af, bfr, acc[n], 0, 0, 0);
        }
    }

    // ---- tail: 4 rows per thread (row = wid*16 + lgp*4 + j) ----
    #pragma unroll
    for (int j = 0; j < 4; ++j) {
        int row = wid * 16 + lgp * 4 + j;
        size_t e = rowbase + row;
        int snd = senders[e];          // 16-lane broadcast loads
        unsigned jj = jof[e];
        uint4 sv = Sp4[(size_t)snd * 16 + l15];
        unsigned uo[4];
        #pragma unroll
        for (int h = 0; h < 4; ++h) {
            unsigned sp = (h == 0) ? sv.x : (h == 1) ? sv.y : (h == 2) ? sv.z : sv.w;
            float elo = acc[2 * h][j]     + bf16lo_to_f32(sp);
            float ehi = acc[2 * h + 1][j] + bf16hi_to_f32(sp);
            uo[h] = pack2_bf16(elo, ehi);
        }
        EAp[(size_t)jj * 16 + l15] = make_uint4(uo[0], uo[1], uo[2], uo[3]);
    }
}

// ---------- fused logit + single-pass softmax + aggregate ----------
// One wave per receiver. Lane remap: h = lane>>4 (head), q = lane&15
// (col class) -> the 16 reduction lanes are CONTIGUOUS, so the per-head
// sum uses 4 DPP VALU adds (no DS cross-lane ops).
__global__ __launch_bounds__(256) void agg_kernel(
    const unsigned* __restrict__ rowptr,
    const unsigned* __restrict__ Rp32,
    const float* __restrict__ attw, const float* __restrict__ attb,
    const unsigned* __restrict__ EA, float* __restrict__ out)
{
    const int lane = threadIdx.x & 63;
    const int r = blockIdx.x * 4 + (threadIdx.x >> 6);
    if (r >= NN) return;
    const unsigned start = rowptr[r], end = rowptr[r + 1];

    const int h = lane >> 4;        // head
    const int q = lane & 15;        // col class
    const int k = q * 4 + h;        // dword index within 256B row
    const int c0 = 32 * h + q;

    if (start == end) {
        out[(size_t)r * HD + c0]      = 0.f;
        out[(size_t)r * HD + c0 + 16] = 0.f;
        return;
    }

    unsigned rp = Rp32[(size_t)r * 64 + k];
    const float rlo = bf16lo_to_f32(rp), rhi = bf16hi_to_f32(rp);
    const float aw0 = attw[q];
    const float aw1 = attw[q + 16];
    const float ab0 = attb[0];
    const unsigned* ea = EA + k;

    float ax0 = 0.f, ay0 = 0.f, dn0 = 0.f;
    float ax1 = 0.f, ay1 = 0.f, dn1 = 0.f;
    unsigned j = start;
    for (; j + 2 <= end; j += 2) {
        unsigned p0 = ea[(size_t)j * 64];
        unsigned p1 = ea[(size_t)(j + 1) * 64];
        float e0l = bf16lo_to_f32(p0), e0h = bf16hi_to_f32(p0);
        float e1l = bf16lo_to_f32(p1), e1h = bf16hi_to_f32(p1);
        float t0 = mish_f(e0l + rlo) * aw0 + mish_f(e0h + rhi) * aw1;
        float t1 = mish_f(e1l + rlo) * aw0 + mish_f(e1h + rhi) * aw1;
        DPP_ADD(t0, 0xB1);  DPP_ADD(t1, 0xB1);   // quad_perm [1,0,3,2]
        DPP_ADD(t0, 0x4E);  DPP_ADD(t1, 0x4E);   // quad_perm [2,3,0,1]
        DPP_ADD(t0, 0x141); DPP_ADD(t1, 0x141);  // row_half_mirror
        DPP_ADD(t0, 0x140); DPP_ADD(t1, 0x140);  // row_mirror
        float w0 = __expf(t0 + ab0);
        float w1 = __expf(t1 + ab0);
        dn0 += w0;  ax0 += w0 * e0l;  ay0 += w0 * e0h;
        dn1 += w1;  ax1 += w1 * e1l;  ay1 += w1 * e1h;
    }
    if (j < end) {
        unsigned p0 = ea[(size_t)j * 64];
        float e0l = bf16lo_to_f32(p0), e0h = bf16hi_to_f32(p0);
        float t0 = mish_f(e0l + rlo) * aw0 + mish_f(e0h + rhi) * aw1;
        DPP_ADD(t0, 0xB1);
        DPP_ADD(t0, 0x4E);
        DPP_ADD(t0, 0x141);
        DPP_ADD(t0, 0x140);
        float w0 = __expf(t0 + ab0);
        dn0 += w0;  ax0 += w0 * e0l;  ay0 += w0 * e0h;
    }
    float rd = 1.f / (dn0 + dn1);
    out[(size_t)r * HD + c0]      = (ax0 + ax1) * rd;
    out[(size_t)r * HD + c0 + 16] = (ay0 + ay1) * rd;
}

// ---------- host ----------
extern "C" void kernel_launch(void* const* d_in, const int* in_sizes, int n_in,
                              void* d_out, int out_size, void* d_ws, size_t ws_size,
                              hipStream_t stream) {
    const float* nodes = (const float*)d_in[0];
    const float* edges = (const float*)d_in[1];
    const float* Ws_k  = (const float*)d_in[2];
    const float* Ws_b  = (const float*)d_in[3];
    const float* Wr_k  = (const float*)d_in[4];
    const float* Wr_b  = (const float*)d_in[5];
    const float* We_k  = (const float*)d_in[6];
    const float* We_b  = (const float*)d_in[7];
    const float* attw  = (const float*)d_in[8];
    const float* attb  = (const float*)d_in[9];
    const int* senders   = (const int*)d_in[10];
    const int* receivers = (const int*)d_in[11];
    float* out = (float*)d_out;

    char* ws = (char*)d_ws;
    const size_t CNT_OFF  = 0;            // 200,000
    const size_t CNT2_OFF = 200000;       // 200,000
    const size_t RP_OFF   = 400000;       // 200,004
    const size_t BS_OFF   = 600004;       // 1,024 (bsum)
    const size_t JOF_OFF  = 700000;       // 3,200,000 -> ends 3,900,000
    const size_t WF_OFF   = 3900000;      // 98,304    -> ends 3,998,304
    const size_t SP_OFF   = 4000000;      // 12,800,000 (bf16) -> 16.8e6
    const size_t RPP_OFF  = 16800000;     // 12,800,000 -> 29.6e6
    const size_t EA_OFF   = 29600000;     // 204,800,000 -> 234.4e6

    unsigned* cnt    = (unsigned*)(ws + CNT_OFF);
    unsigned* cnt2   = (unsigned*)(ws + CNT2_OFF);
    unsigned* rowptr = (unsigned*)(ws + RP_OFF);
    unsigned* bsum   = (unsigned*)(ws + BS_OFF);
    unsigned* jof    = (unsigned*)(ws + JOF_OFF);
    uint4*    Wf     = (uint4*)(ws + WF_OFF);
    uint2*    Sp     = (uint2*)(ws + SP_OFF);
    uint2*    Rp     = (uint2*)(ws + RPP_OFF);
    unsigned* EA     = (unsigned*)(ws + EA_OFF);
    (void)ws_size;

    const int NB = (NN + 255) / 256;   // 196 scan blocks

    // weights -> bf16 fragment order; extra blocks zero cnt/cnt2
    prep_w<<<3 + 98, 256, 0, stream>>>(Ws_k, Wr_k, We_k, Wf, (uint4*)(ws + CNT_OFF));

    // CSR build (rowptr + inverse perm map jof), multi-block scan
    hist_kernel<<<(NE + 255) / 256, 256, 0, stream>>>(receivers, cnt);
    scan1_kernel<<<NB, 256, 0, stream>>>(cnt, rowptr, bsum);
    scan3_kernel<<<NB, 256, 0, stream>>>(rowptr, bsum, NB);
    scatter_kernel<<<(NE + 255) / 256, 256, 0, stream>>>(receivers, rowptr, cnt2, jof);

    // both node projections (bf16 head-interleaved packed output)
    proj_both<<<(NN + 127) / 128, 256, 0, stream>>>(
        nodes, (const bf16x8*)Wf, (const bf16x8*)(Wf + 2048),
        Ws_b, Wr_b, NN, Sp, Rp);

    // edge GEMM: EA written at perm positions (no LDS, no barriers)
    edge_gemm<<<NE / 64, 256, 0, stream>>>(
        edges, (const bf16x8*)(Wf + 4096), We_b,
        senders, jof, (const uint4*)Sp, (uint4*)EA);

    // fused logit + single-pass softmax + aggregation (DPP reduce)
    agg_kernel<<<(NN + 3) / 4, 256, 0, stream>>>(
        rowptr, (const unsigned*)Rp, attw, attb, EA, out);
}

// Round 15
// 359.495 us; speedup vs baseline: 1.0959x; 1.0324x over previous
//
#include <hip/hip_runtime.h>
#include <hip/hip_bf16.h>

#define NN 50000
#define NE 800000
#define F 128     // input feature dim (= K)
#define HD 128    // output dim = H*DH (= N)
#define H 4

typedef __attribute__((ext_vector_type(4))) float f32x4;
typedef __attribute__((ext_vector_type(8))) __bf16 bf16x8;
typedef __attribute__((ext_vector_type(2))) __bf16 bf16x2;

// ---------- helpers ----------

// mish(x) = x * tanh(softplus(x)) = x * (u-1)/(u+1), u = (1+e^x)^2
__device__ __forceinline__ float mish_f(float x) {
    if (x > 30.f) return x;
    float t = __expf(x);
    float u = 1.f + t;
    u = u * u;
    return x * (u - 1.f) * __builtin_amdgcn_rcpf(u + 1.f);
}

// packed f32x2 -> bf16x2 (compiler emits v_cvt_pk_bf16_f32, RNE)
__device__ __forceinline__ unsigned pack2_bf16(float a, float b) {
    bf16x2 v;
    v.x = (__bf16)a;
    v.y = (__bf16)b;
    return __builtin_bit_cast(unsigned, v);
}
__device__ __forceinline__ float bf16lo_to_f32(unsigned p) {
    return __uint_as_float((p & 0xFFFFu) << 16);
}
__device__ __forceinline__ float bf16hi_to_f32(unsigned p) {
    return __uint_as_float(p & 0xFFFF0000u);
}

// DPP-based add: v += lane-permuted v within a row of 16 (VALU, no DS)
#define DPP_ADD(v, ctrl)                                                     \
    (v) += __int_as_float(__builtin_amdgcn_update_dpp(                       \
        0, __float_as_int(v), (ctrl), 0xf, 0xf, true))

// ---------- prep: W -> bf16 fragment-ordered; extra blocks zero cnt/cnt2 ----------
__global__ __launch_bounds__(256) void prep_w(
    const float* __restrict__ W0, const float* __restrict__ W1,
    const float* __restrict__ W2, uint4* __restrict__ O,
    uint4* __restrict__ zero_dst)   // 400,000 B = 25,000 uint4
{
    int b = blockIdx.x;
    if (b >= 3) {
        int i = (b - 3) * 256 + threadIdx.x;
        if (i < 25000) zero_dst[i] = make_uint4(0, 0, 0, 0);
        return;
    }
    const float* W = (b == 0) ? W0 : (b == 1) ? W1 : W2;
    uint4* out = O + b * 2048;
    for (int c = threadIdx.x; c < 2048; c += 256) {
        int fn = c >> 8, ks = (c >> 6) & 3, lane = c & 63;
        int lgp = lane >> 4, l15 = lane & 15;
        int col = fn * 16 + l15, k0 = ks * 32 + lgp * 8;
        unsigned u[4];
        #pragma unroll
        for (int i = 0; i < 4; ++i)
            u[i] = pack2_bf16(W[(k0 + 2 * i) * 128 + col],
                              W[(k0 + 2 * i + 1) * 128 + col]);
        out[c] = make_uint4(u[0], u[1], u[2], u[3]);
    }
}

// ---------- CSR build ----------
__global__ __launch_bounds__(256) void hist_kernel(
    const int* __restrict__ receivers, unsigned* __restrict__ cnt)
{
    int i = blockIdx.x * 256 + threadIdx.x;
    if (i < NE) atomicAdd(&cnt[receivers[i]], 1u);
}

// scan phase 1: per-block exclusive scan of 256 counts + block sum
__global__ __launch_bounds__(256) void scan1_kernel(
    const unsigned* __restrict__ cnt, unsigned* __restrict__ rowptr,
    unsigned* __restrict__ bsum)
{
    __shared__ unsigned sh[256];
    const int t = threadIdx.x;
    int i = blockIdx.x * 256 + t;
    unsigned c = (i < NN) ? cnt[i] : 0u;
    sh[t] = c;
    __syncthreads();
    unsigned incl = c;
    for (int off = 1; off < 256; off <<= 1) {
        unsigned v = (t >= off) ? sh[t - off] : 0u;
        __syncthreads();
        incl += v;
        sh[t] = incl;
        __syncthreads();
    }
    if (i < NN) rowptr[i] = incl - c;      // exclusive within block
    if (t == 255) bsum[blockIdx.x] = incl; // block total
}

// scan phase 2+3 fused: each block redundantly scans the block sums,
// picks its own offset, adds it.
__global__ __launch_bounds__(256) void scan3_kernel(
    unsigned* __restrict__ rowptr, const unsigned* __restrict__ bsum, int nb)
{
    __shared__ unsigned sh[256];
    __shared__ unsigned s_off;
    const int t = threadIdx.x;
    unsigned c = (t < nb) ? bsum[t] : 0u;
    sh[t] = c;
    __syncthreads();
    unsigned incl = c;
    for (int off = 1; off < 256; off <<= 1) {
        unsigned v = (t >= off) ? sh[t - off] : 0u;
        __syncthreads();
        incl += v;
        sh[t] = incl;
        __syncthreads();
    }
    if (t == 0) {
        s_off = (blockIdx.x > 0) ? sh[blockIdx.x - 1] : 0u;
        if (blockIdx.x == 0) rowptr[NN] = NE;
    }
    __syncthreads();
    int i = blockIdx.x * 256 + t;
    if (i < NN) rowptr[i] += s_off;
}

// scatter + inverse map jof: edge e lands at perm position jof[e]
__global__ __launch_bounds__(256) void scatter_kernel(
    const int* __restrict__ receivers, const unsigned* __restrict__ rowptr,
    unsigned* __restrict__ cnt2, unsigned* __restrict__ jof)
{
    int i = blockIdx.x * 256 + threadIdx.x;
    if (i >= NE) return;
    int r = receivers[i];
    unsigned pos = rowptr[r] + atomicAdd(&cnt2[r], 1u);
    jof[i] = pos;
}

// ---------- both node projections in one kernel ----------
// Sp/Rp layout (bf16, head-interleaved): node row = 64 uints (256 B);
// uint k = l15*4 + h holds cols (32h + l15, 32h + 16 + l15) as 2 bf16.
__global__ __launch_bounds__(256, 4) void proj_both(
    const float* __restrict__ X,
    const bf16x8* __restrict__ Wf0, const bf16x8* __restrict__ Wf1,
    const float* __restrict__ b0, const float* __restrict__ b1,
    int M, uint2* __restrict__ Sp, uint2* __restrict__ Rp)
{
    __shared__ __align__(16) char ldsA[32768];
    const int t = threadIdx.x;
    const int lane = t & 63;
    const int wid = t >> 6;
    const int wr = wid >> 1, wc = wid & 1;
    const int l15 = lane & 15, lgp = lane >> 4;
    const size_t rowbase = (size_t)blockIdx.x * 128;

    #pragma unroll
    for (int i = 0; i < 8; ++i) {
        int c = i * 256 + t;
        int row = c >> 4, cc = c & 15;
        size_t e = rowbase + row;
        uint4 p = make_uint4(0, 0, 0, 0);
        if (e < (size_t)M) {
            const float4* src = (const float4*)(X + e * F + cc * 8);
            float4 f0 = src[0], f1 = src[1];
            p.x = pack2_bf16(f0.x, f0.y);
            p.y = pack2_bf16(f0.z, f0.w);
            p.z = pack2_bf16(f1.x, f1.y);
            p.w = pack2_bf16(f1.z, f1.w);
        }
        unsigned byte = (unsigned)(row * 256 + cc * 16);
        byte ^= (unsigned)((row & 7) << 4);
        *(uint4*)(ldsA + byte) = p;
    }
    __syncthreads();

    #pragma unroll
    for (int pass = 0; pass < 2; ++pass) {
        const bf16x8* Wf = pass ? Wf1 : Wf0;
        const float* bias = pass ? b1 : b0;
        uint2* Y = pass ? Rp : Sp;

        f32x4 acc[4][4];
        #pragma unroll
        for (int n = 0; n < 4; ++n) {
            float bv = bias[wc * 64 + n * 16 + l15];
            #pragma unroll
            for (int m = 0; m < 4; ++m) {
                acc[m][n][0] = bv; acc[m][n][1] = bv;
                acc[m][n][2] = bv; acc[m][n][3] = bv;
            }
        }
        #pragma unroll
        for (int ks = 0; ks < 4; ++ks) {
            const int kb = ks * 64 + lgp * 16;
            bf16x8 af[4], bfr[4];
            #pragma unroll
            for (int m = 0; m < 4; ++m) {
                int row = wr * 64 + m * 16 + l15;
                unsigned byte = ((unsigned)(row * 256 + kb)) ^ ((row & 7) << 4);
                af[m] = *(const bf16x8*)(ldsA + byte);
            }
            #pragma unroll
            for (int n = 0; n < 4; ++n)
                bfr[n] = Wf[((wc * 4 + n) * 4 + ks) * 64 + lane];
            #pragma unroll
            for (int m = 0; m < 4; ++m)
                #pragma unroll
                for (int n = 0; n < 4; ++n)
                    acc[m][n] = __builtin_amdgcn_mfma_f32_16x16x32_bf16(
                        af[m], bfr[n], acc[m][n], 0, 0, 0);
        }
        // store: this thread's cols are heads wc*2 + {0,1}, col-class l15
        #pragma unroll
        for (int m = 0; m < 4; ++m)
            #pragma unroll
            for (int j = 0; j < 4; ++j) {
                int row = wr * 64 + m * 16 + lgp * 4 + j;
                size_t e = rowbase + row;
                if (e >= (size_t)M) continue;
                uint2 pk;
                pk.x = pack2_bf16(acc[m][0][j], acc[m][1][j]);
                pk.y = pack2_bf16(acc[m][2][j], acc[m][3][j]);
                Y[e * 32 + l15 * 2 + wc] = pk;   // uints k = l15*4 + wc*2 + {0,1}
            }
    }
}

// ---------- edge GEMM: BM=64, NO LDS, NO barriers ----------
__global__ __launch_bounds__(256, 8) void edge_gemm(
    const float* __restrict__ X, const bf16x8* __restrict__ Wf,
    const float* __restrict__ bias,
    const int* __restrict__ senders, const unsigned* __restrict__ jof,
    const uint4* __restrict__ Sp4, uint4* __restrict__ EAp)
{
    const int t = threadIdx.x;
    const int lane = t & 63;
    const int wid = t >> 6;
    const int l15 = lane & 15, lgp = lane >> 4;
    const size_t rowbase = (size_t)blockIdx.x * 64;
    const float* aptr = X + (rowbase + wid * 16 + l15) * F;

    f32x4 acc[8];
    #pragma unroll
    for (int n = 0; n < 8; ++n) {
        float bv = bias[n * 16 + l15];
        acc[n][0] = bv; acc[n][1] = bv; acc[n][2] = bv; acc[n][3] = bv;
    }

    #pragma unroll
    for (int ks = 0; ks < 4; ++ks) {
        const float4* ap = (const float4*)(aptr + ks * 32 + lgp * 8);
        float4 a0 = ap[0], a1 = ap[1];
        uint4 pu;
        pu.x = pack2_bf16(a0.x, a0.y);
        pu.y = pack2_bf16(a0.z, a0.w);
        pu.z = pack2_bf16(a1.x, a1.y);
        pu.w = pack2_bf16(a1.z, a1.w);
        bf16x8 af = __builtin_bit_cast(bf16x8, pu);
        #pragma unroll
        for (int n = 0; n < 8; ++n) {
            bf16x8 bfr = Wf[(n * 4 + ks) * 64 + lane];
            acc[n] = __builtin_amdgcn_mfma_f32_16x16x32_bf16(af, bfr, acc[n], 0, 0, 0);
        }
    }

    // ---- tail: 4 rows per thread (row = wid*16 + lgp*4 + j) ----
    #pragma unroll
    for (int j = 0; j < 4; ++j) {
        int row = wid * 16 + lgp * 4 + j;
        size_t e = rowbase + row;
        int snd = senders[e];          // 16-lane broadcast loads
        unsigned jj = jof[e];
        uint4 sv = Sp4[(size_t)snd * 16 + l15];
        unsigned uo[4];
        #pragma unroll
        for (int h = 0; h < 4; ++h) {
            unsigned sp = (h == 0) ? sv.x : (h == 1) ? sv.y : (h == 2) ? sv.z : sv.w;
            float elo = acc[2 * h][j]     + bf16lo_to_f32(sp);
            float ehi = acc[2 * h + 1][j] + bf16hi_to_f32(sp);
            uo[h] = pack2_bf16(elo, ehi);
        }
        EAp[(size_t)jj * 16 + l15] = make_uint4(uo[0], uo[1], uo[2], uo[3]);
    }
}

// ---------- fused logit + single-pass softmax + aggregate ----------
// One wave per receiver; DPP 16-lane reduce; 4-deep software pipeline
// (next quad's loads issued before current quad's compute) with 4
// independent accumulator banks for MLP/ILP.
__global__ __launch_bounds__(256) void agg_kernel(
    const unsigned* __restrict__ rowptr,
    const unsigned* __restrict__ Rp32,
    const float* __restrict__ attw, const float* __restrict__ attb,
    const unsigned* __restrict__ EA, float* __restrict__ out)
{
    const int lane = threadIdx.x & 63;
    const int r = blockIdx.x * 4 + (threadIdx.x >> 6);
    if (r >= NN) return;
    const unsigned start = rowptr[r], end = rowptr[r + 1];

    const int h = lane >> 4;        // head
    const int q = lane & 15;        // col class
    const int k = q * 4 + h;        // dword index within 256B row
    const int c0 = 32 * h + q;

    if (start == end) {
        out[(size_t)r * HD + c0]      = 0.f;
        out[(size_t)r * HD + c0 + 16] = 0.f;
        return;
    }

    unsigned rp = Rp32[(size_t)r * 64 + k];
    const float rlo = bf16lo_to_f32(rp), rhi = bf16hi_to_f32(rp);
    const float aw0 = attw[q];
    const float aw1 = attw[q + 16];
    const float ab0 = attb[0];
    const unsigned* ea = EA + k;

#define PROC(P, AX, AY, DN) do {                                             \
        float el_ = bf16lo_to_f32(P), eh_ = bf16hi_to_f32(P);                \
        float tt_ = mish_f(el_ + rlo) * aw0 + mish_f(eh_ + rhi) * aw1;       \
        DPP_ADD(tt_, 0xB1);  DPP_ADD(tt_, 0x4E);                             \
        DPP_ADD(tt_, 0x141); DPP_ADD(tt_, 0x140);                            \
        float w_ = __expf(tt_ + ab0);                                        \
        DN += w_; AX += w_ * el_; AY += w_ * eh_; } while (0)

    float ax0 = 0.f, ay0 = 0.f, dn0 = 0.f;
    float ax1 = 0.f, ay1 = 0.f, dn1 = 0.f;
    float ax2 = 0.f, ay2 = 0.f, dn2 = 0.f;
    float ax3 = 0.f, ay3 = 0.f, dn3 = 0.f;

    unsigned cnt = end - start;
    unsigned nq = cnt >> 2;
    unsigned j = start;
    if (nq) {
        const unsigned* e0 = ea + (size_t)start * 64;
        unsigned p0 = e0[0], p1 = e0[64], p2 = e0[128], p3 = e0[192];
        for (unsigned qq = 1; qq < nq; ++qq) {
            const unsigned* en = ea + (size_t)(start + qq * 4) * 64;
            unsigned n0 = en[0], n1 = en[64], n2 = en[128], n3 = en[192];
            PROC(p0, ax0, ay0, dn0);
            PROC(p1, ax1, ay1, dn1);
            PROC(p2, ax2, ay2, dn2);
            PROC(p3, ax3, ay3, dn3);
            p0 = n0; p1 = n1; p2 = n2; p3 = n3;
        }
        PROC(p0, ax0, ay0, dn0);
        PROC(p1, ax1, ay1, dn1);
        PROC(p2, ax2, ay2, dn2);
        PROC(p3, ax3, ay3, dn3);
        j = start + nq * 4;
    }
    for (; j < end; ++j) {
        unsigned p = ea[(size_t)j * 64];
        PROC(p, ax0, ay0, dn0);
    }
#undef PROC

    float rd = 1.f / (dn0 + dn1 + dn2 + dn3);
    out[(size_t)r * HD + c0]      = (ax0 + ax1 + ax2 + ax3) * rd;
    out[(size_t)r * HD + c0 + 16] = (ay0 + ay1 + ay2 + ay3) * rd;
}

// ---------- host ----------
extern "C" void kernel_launch(void* const* d_in, const int* in_sizes, int n_in,
                              void* d_out, int out_size, void* d_ws, size_t ws_size,
                              hipStream_t stream) {
    const float* nodes = (const float*)d_in[0];
    const float* edges = (const float*)d_in[1];
    const float* Ws_k  = (const float*)d_in[2];
    const float* Ws_b  = (const float*)d_in[3];
    const float* Wr_k  = (const float*)d_in[4];
    const float* Wr_b  = (const float*)d_in[5];
    const float* We_k  = (const float*)d_in[6];
    const float* We_b  = (const float*)d_in[7];
    const float* attw  = (const float*)d_in[8];
    const float* attb  = (const float*)d_in[9];
    const int* senders   = (const int*)d_in[10];
    const int* receivers = (const int*)d_in[11];
    float* out = (float*)d_out;

    char* ws = (char*)d_ws;
    const size_t CNT_OFF  = 0;            // 200,000
    const size_t CNT2_OFF = 200000;       // 200,000
    const size_t RP_OFF   = 400000;       // 200,004
    const size_t BS_OFF   = 600004;       // 1,024 (bsum)
    const size_t JOF_OFF  = 700000;       // 3,200,000 -> ends 3,900,000
    const size_t WF_OFF   = 3900000;      // 98,304    -> ends 3,998,304
    const size_t SP_OFF   = 4000000;      // 12,800,000 (bf16) -> 16.8e6
    const size_t RPP_OFF  = 16800000;     // 12,800,000 -> 29.6e6
    const size_t EA_OFF   = 29600000;     // 204,800,000 -> 234.4e6

    unsigned* cnt    = (unsigned*)(ws + CNT_OFF);
    unsigned* cnt2   = (unsigned*)(ws + CNT2_OFF);
    unsigned* rowptr = (unsigned*)(ws + RP_OFF);
    unsigned* bsum   = (unsigned*)(ws + BS_OFF);
    unsigned* jof    = (unsigned*)(ws + JOF_OFF);
    uint4*    Wf     = (uint4*)(ws + WF_OFF);
    uint2*    Sp     = (uint2*)(ws + SP_OFF);
    uint2*    Rp     = (uint2*)(ws + RPP_OFF);
    unsigned* EA     = (unsigned*)(ws + EA_OFF);
    (void)ws_size;

    const int NB = (NN + 255) / 256;   // 196 scan blocks

    // weights -> bf16 fragment order; extra blocks zero cnt/cnt2
    prep_w<<<3 + 98, 256, 0, stream>>>(Ws_k, Wr_k, We_k, Wf, (uint4*)(ws + CNT_OFF));

    // CSR build (rowptr + inverse perm map jof), multi-block scan
    hist_kernel<<<(NE + 255) / 256, 256, 0, stream>>>(receivers, cnt);
    scan1_kernel<<<NB, 256, 0, stream>>>(cnt, rowptr, bsum);
    scan3_kernel<<<NB, 256, 0, stream>>>(rowptr, bsum, NB);
    scatter_kernel<<<(NE + 255) / 256, 256, 0, stream>>>(receivers, rowptr, cnt2, jof);

    // both node projections (bf16 head-interleaved packed output)
    proj_both<<<(NN + 127) / 128, 256, 0, stream>>>(
        nodes, (const bf16x8*)Wf, (const bf16x8*)(Wf + 2048),
        Ws_b, Wr_b, NN, Sp, Rp);

    // edge GEMM: EA written at perm positions (no LDS, no barriers)
    edge_gemm<<<NE / 64, 256, 0, stream>>>(
        edges, (const bf16x8*)(Wf + 4096), We_b,
        senders, jof, (const uint4*)Sp, (uint4*)EA);

    // fused logit + single-pass softmax + aggregation (4-deep pipeline)
    agg_kernel<<<(NN + 3) / 4, 256, 0, stream>>>(
        rowptr, (const unsigned*)Rp, attw, attb, EA, out);
}